// Round 10
// baseline (262.731 us; speedup 1.0000x reference)
//
#include <hip/hip_runtime.h>
#include <hip/hip_fp16.h>
#include <math.h>

#define BLK 256

// ---------------------------------------------------------------------------
// GCNPolicyNetwork: 3-layer improved-GCN + masked softmax + mean-pool value.
// Round 10: degree-sorted processing order. R9 showed k_agg2 at 39% occupancy
// with VALUBusy 12% -> wave-level imbalance (wave waits on max of 16 Poisson
// degrees ~47 vs mean 32). k_place now counting-sorts each 256-node bucket by
// degree into perm[] (slot -> node id, -1 pad); agg kernels process
// i = perm[slot], so each wave's 16 node-groups have ~equal trip counts.
// Gather structure unchanged from R9 (node-centric 4-lane fp16, unroll x8 —
// best known; R6 remap/R7 edge-centric both regressed).
// ---------------------------------------------------------------------------

#define BSH 8                    // 256 nodes per bucket
#define NB 512                   // bucket-array size (nbuck=391 <= 512)
#define CAP 10240                // packed[] capacity per bucket (mean ~8184)
#define EB 8192                  // edges per binning block
#define BINTH 512                // k_bin block size
#define DCLIP 72                 // degree-histogram bins for the local sort

// ---- fp16 payload helpers ----
__device__ inline float4 load_h4(const __half* base, int node, int sub) {
    const uint2* p = reinterpret_cast<const uint2*>(base + ((size_t)node << 4)) + sub;
    uint2 u = *p;
    union { unsigned u; __half2 h; } a, b;
    a.u = u.x; b.u = u.y;
    float2 fa = __half22float2(a.h), fb = __half22float2(b.h);
    return make_float4(fa.x, fa.y, fb.x, fb.y);
}

__device__ inline void store_h4(__half* base, int node, int sub, float4 v) {
    union { unsigned u; __half2 h; } a, b;
    a.h = __floats2half2_rn(v.x, v.y);
    b.h = __floats2half2_rn(v.z, v.w);
    uint2 u; u.x = a.u; u.y = b.u;
    *(reinterpret_cast<uint2*>(base + ((size_t)node << 4)) + sub) = u;
}

// xs payload: half4 (dinv*x0, dinv*x1, dinv*x2, 0) = 8 B per node
__device__ inline float3 load_xs(const __half* xs, int node) {
    uint2 u = *reinterpret_cast<const uint2*>(xs + ((size_t)node << 2));
    union { unsigned u; __half2 h; } a, b;
    a.u = u.x; b.u = u.y;
    float2 fa = __half22float2(a.h), fb = __half22float2(b.h);
    return make_float3(fa.x, fa.y, fb.x);
}

// monotone float<->uint encoding for atomicMax over signed floats
__device__ inline unsigned encf(float f) {
    unsigned u = __float_as_uint(f);
    return (u & 0x80000000u) ? ~u : (u | 0x80000000u);
}
__device__ inline float decf(unsigned e) {
    return (e & 0x80000000u) ? __uint_as_float(e ^ 0x80000000u)
                             : __uint_as_float(~e);
}

// zero gcur[NB] + scal[18] (Ssum, pool[16], maxenc)
__global__ void k_init(int* __restrict__ gcur, float* __restrict__ scal) {
    int t = threadIdx.x;
    gcur[t] = 0;
    if (t < 18) scal[t] = 0.f;
}

// LDS multisplit of edges into 256-node buckets; reserve directly in the
// fixed-capacity packed[] layout (bucket b owns [b*CAP, b*CAP+cnt)).
__global__ void __launch_bounds__(BINTH) k_bin(const int* __restrict__ row,
                                               const int* __restrict__ col,
                                               int* __restrict__ gcur,
                                               int* __restrict__ packed, int E) {
    __shared__ int stage[EB];
    __shared__ unsigned short sbuk[EB];
    __shared__ int hist[NB];
    __shared__ int lscan[NB];
    __shared__ int cur[NB];
    __shared__ int gbase[NB];
    int tid = threadIdx.x;
    int base = blockIdx.x * EB;
    int cnt = min(EB, E - base);

    hist[tid] = 0;
    __syncthreads();
    for (int j = tid; j < cnt; j += BINTH) {
        int c = __builtin_nontemporal_load(col + base + j);
        atomicAdd(&hist[c >> BSH], 1);
    }
    __syncthreads();
    lscan[tid] = hist[tid];
    __syncthreads();
    for (int d = 1; d < NB; d <<= 1) {
        int t = (tid >= d) ? lscan[tid - d] : 0;
        __syncthreads();
        if (tid >= d) lscan[tid] += t;
        __syncthreads();
    }
    {
        int ex = lscan[tid] - hist[tid];
        lscan[tid] = ex;
        cur[tid] = ex;
    }
    __syncthreads();
    for (int j = tid; j < cnt; j += BINTH) {
        int c = __builtin_nontemporal_load(col + base + j);
        int r = __builtin_nontemporal_load(row + base + j);
        int b = c >> BSH;
        int p = atomicAdd(&cur[b], 1);
        stage[p] = (r << BSH) | (c & ((1 << BSH) - 1));
        sbuk[p] = (unsigned short)b;
    }
    __syncthreads();
    if (hist[tid] > 0) gbase[tid] = tid * CAP + atomicAdd(&gcur[tid], hist[tid]);
    __syncthreads();
    for (int j = tid; j < cnt; j += BINTH) {
        int b = sbuk[j];
        int pos = gbase[b] + (j - lscan[b]);
        packed[pos] = stage[j];
    }
}

// per-bucket: tight CSR base + degree hist/scan -> degi/offs/dinv/xs,
// fine placement into srcs, and bucket-local degree counting sort -> perm.
__global__ void __launch_bounds__(BLK) k_place(const int* __restrict__ packed,
                                               const int* __restrict__ bcnt,
                                               const float* __restrict__ x,
                                               int* __restrict__ degi,
                                               int* __restrict__ offs,
                                               float* __restrict__ dinv,
                                               __half* __restrict__ xs,
                                               int* __restrict__ srcs,
                                               int* __restrict__ perm, int n) {
    __shared__ int cnt[256];
    __shared__ int lcur[256];
    __shared__ int ssum[256];
    __shared__ int psum[256];
    __shared__ int dh[DCLIP];
    __shared__ int dbase[DCLIP];
    int tid = threadIdx.x;
    int b = blockIdx.x;
    int nb0 = b << BSH;
    // tight base: sum of bcnt[b'] for b' < b
    int pv = 0;
    for (int t = tid; t < b; t += BLK) pv += bcnt[t];
    psum[tid] = pv;
    cnt[tid] = 0;
    if (tid < DCLIP) dh[tid] = 0;
    __syncthreads();
    for (int d = BLK / 2; d > 0; d >>= 1) {
        if (tid < d) psum[tid] += psum[tid + d];
        __syncthreads();
    }
    int pbeg = psum[0];
    int ecnt = bcnt[b];
    const int* pk = packed + (size_t)b * CAP;
    for (int j = tid; j < ecnt; j += BLK)
        atomicAdd(&cnt[pk[j] & 255], 1);
    __syncthreads();
    int c = cnt[tid];
    ssum[tid] = c;
    __syncthreads();
    for (int d = 1; d < 256; d <<= 1) {
        int t = (tid >= d) ? ssum[tid - d] : 0;
        __syncthreads();
        if (tid >= d) ssum[tid] += t;
        __syncthreads();
    }
    int ex = ssum[tid] - c;
    lcur[tid] = ex;
    int valid = min(n - nb0, 256);
    int i = nb0 + tid;
    int dc = (c > DCLIP - 1) ? DCLIP - 1 : c;
    if (tid < valid) {
        degi[i] = c;
        offs[i] = pbeg + ex;
        float di = rsqrtf((float)c + 2.0f);
        dinv[i] = di;
        float x0 = x[i * 3 + 0], x1 = x[i * 3 + 1], x2 = x[i * 3 + 2];
        union { unsigned u; __half2 h; } a2, b2;
        a2.h = __floats2half2_rn(di * x0, di * x1);
        b2.h = __floats2half2_rn(di * x2, 0.f);
        uint2 u; u.x = a2.u; u.y = b2.u;
        *reinterpret_cast<uint2*>(xs + ((size_t)i << 2)) = u;
        atomicAdd(&dh[dc], 1);          // degree histogram for the local sort
    }
    __syncthreads();
    if (tid == 0) {
        int run = 0;
#pragma unroll 1
        for (int d = 0; d < DCLIP; d++) { dbase[d] = run; run += dh[d]; dh[d] = 0; }
    }
    __syncthreads();
    // counting-sort placement: slot ranks [0,valid) exactly; pads disjoint
    if (tid < valid) {
        int r = atomicAdd(&dh[dc], 1);
        perm[(b << 8) + dbase[dc] + r] = i;
    } else {
        perm[(b << 8) + tid] = -1;
    }
    __syncthreads();
    for (int j = tid; j < ecnt; j += BLK) {
        int v = pk[j];
        int li = v & 255;
        int slot = atomicAdd(&lcur[li], 1);
        srcs[pbeg + slot] = v >> BSH;
    }
}

// layer-1: rank-3 aggregation of xs, then @W1 + relu, then @W2 -> hwsB (fp16).
__global__ void __launch_bounds__(BLK) k_agg1(const __half* __restrict__ xs,
                                              const int* __restrict__ offs,
                                              const int* __restrict__ degi,
                                              const int* __restrict__ srcs,
                                              const float* __restrict__ dinv,
                                              const int* __restrict__ perm,
                                              const float* __restrict__ b1,
                                              const float* __restrict__ W1,
                                              const float* __restrict__ W2,
                                              __half* __restrict__ hwsB, int n) {
    __shared__ float w1[48];
    __shared__ float w2[256];
    __shared__ float bb[16];
    __shared__ float hbuf[64][17];
    int tid = threadIdx.x;
    w2[tid] = W2[tid];
    if (tid < 48) w1[tid] = W1[tid];
    if (tid < 16) bb[tid] = b1[tid];
    __syncthreads();
    int nl = tid >> 2, sub = tid & 3;
    int i = perm[blockIdx.x * 64 + nl];
    bool act = (i >= 0);
    float di = 0.f;
    if (act) {
        di = dinv[i];
        float ax = 0.f, ay = 0.f, az = 0.f;
        float bx = 0.f, by = 0.f, bz = 0.f;
        int beg = offs[i], end = beg + degi[i];
        int j = beg + sub;
        for (; j + 12 < end; j += 16) {
            int r0 = srcs[j], r1 = srcs[j + 4], r2 = srcs[j + 8], r3 = srcs[j + 12];
            float3 q0 = load_xs(xs, r0);
            float3 q1 = load_xs(xs, r1);
            float3 q2 = load_xs(xs, r2);
            float3 q3 = load_xs(xs, r3);
            ax += q0.x; ay += q0.y; az += q0.z;
            bx += q1.x; by += q1.y; bz += q1.z;
            ax += q2.x; ay += q2.y; az += q2.z;
            bx += q3.x; by += q3.y; bz += q3.z;
        }
        for (; j < end; j += 4) {
            float3 q0 = load_xs(xs, srcs[j]);
            ax += q0.x; ay += q0.y; az += q0.z;
        }
        ax += bx; ay += by; az += bz;
        ax += __shfl_xor(ax, 1); ay += __shfl_xor(ay, 1); az += __shfl_xor(az, 1);
        ax += __shfl_xor(ax, 2); ay += __shfl_xor(ay, 2); az += __shfl_xor(az, 2);
        float3 s = load_xs(xs, i);
        ax += 2.f * s.x; ay += 2.f * s.y; az += 2.f * s.z;
#pragma unroll
        for (int k = 0; k < 4; k++) {
            int f = sub * 4 + k;
            float hv = di * (ax * w1[f] + ay * w1[16 + f] + az * w1[32 + f]) + bb[f];
            hbuf[nl][f] = fmaxf(hv, 0.f);
        }
    }
    __syncthreads();
    if (act) {
        const float* hn = hbuf[nl];
        float s0 = 0.f, s1 = 0.f, s2 = 0.f, s3 = 0.f;
#pragma unroll
        for (int f = 0; f < 16; f++) {
            float hv = hn[f];
            const float4 wq = *(const float4*)&w2[f * 16 + sub * 4];
            s0 += hv * wq.x; s1 += hv * wq.y; s2 += hv * wq.z; s3 += hv * wq.w;
        }
        store_h4(hwsB, i, sub, make_float4(di * s0, di * s1, di * s2, di * s3));
    }
}

// node-centric 4-lane gather, fp16 payload, unroll x8 (srcs batch prefetch)
#define GATHER8H(HWS)                                                           \
    float4 acc;                                                                 \
    {                                                                           \
        float4 s0 = load_h4(HWS, i, sub);                                       \
        acc = make_float4(2.f * s0.x, 2.f * s0.y, 2.f * s0.z, 2.f * s0.w);      \
        float4 a1 = make_float4(0.f, 0.f, 0.f, 0.f);                            \
        float4 a2 = a1, a3 = a1;                                                \
        int beg = offs[i], end = beg + degi[i];                                 \
        int j = beg;                                                            \
        for (; j + 7 < end; j += 8) {                                           \
            int r0 = srcs[j],     r1 = srcs[j + 1], r2 = srcs[j + 2], r3 = srcs[j + 3]; \
            int r4 = srcs[j + 4], r5 = srcs[j + 5], r6 = srcs[j + 6], r7 = srcs[j + 7]; \
            float4 q0 = load_h4(HWS, r0, sub);                                  \
            float4 q1 = load_h4(HWS, r1, sub);                                  \
            float4 q2 = load_h4(HWS, r2, sub);                                  \
            float4 q3 = load_h4(HWS, r3, sub);                                  \
            float4 q4 = load_h4(HWS, r4, sub);                                  \
            float4 q5 = load_h4(HWS, r5, sub);                                  \
            float4 q6 = load_h4(HWS, r6, sub);                                  \
            float4 q7 = load_h4(HWS, r7, sub);                                  \
            acc.x += q0.x + q4.x; acc.y += q0.y + q4.y;                         \
            acc.z += q0.z + q4.z; acc.w += q0.w + q4.w;                         \
            a1.x += q1.x + q5.x; a1.y += q1.y + q5.y;                           \
            a1.z += q1.z + q5.z; a1.w += q1.w + q5.w;                           \
            a2.x += q2.x + q6.x; a2.y += q2.y + q6.y;                           \
            a2.z += q2.z + q6.z; a2.w += q2.w + q6.w;                           \
            a3.x += q3.x + q7.x; a3.y += q3.y + q7.y;                           \
            a3.z += q3.z + q7.z; a3.w += q3.w + q7.w;                           \
        }                                                                       \
        for (; j < end; j++) {                                                  \
            float4 q0 = load_h4(HWS, srcs[j], sub);                             \
            acc.x += q0.x; acc.y += q0.y; acc.z += q0.z; acc.w += q0.w;         \
        }                                                                       \
        acc.x += a1.x + a2.x + a3.x;                                            \
        acc.y += a1.y + a2.y + a3.y;                                            \
        acc.z += a1.z + a2.z + a3.z;                                            \
        acc.w += a1.w + a2.w + a3.w;                                            \
    }

// layer-2 aggregate + relu (-> h2), pool accumulation, layer-3 transform
__global__ void __launch_bounds__(BLK) k_agg2(const __half* __restrict__ hwsB,
                                              const int* __restrict__ offs,
                                              const int* __restrict__ degi,
                                              const int* __restrict__ srcs,
                                              const float* __restrict__ dinv,
                                              const int* __restrict__ perm,
                                              const float* __restrict__ b2,
                                              const float* __restrict__ W3,
                                              float* __restrict__ hws3,
                                              float* __restrict__ pool, int n) {
    __shared__ float w3[16];
    __shared__ float bb[16];
    __shared__ float lp[16];
    int tid = threadIdx.x;
    if (tid < 16) { w3[tid] = W3[tid]; bb[tid] = b2[tid]; lp[tid] = 0.f; }
    __syncthreads();
    int nl = tid >> 2, sub = tid & 3;
    int i = perm[blockIdx.x * 64 + nl];
    bool act = (i >= 0);
    float4 h = make_float4(0.f, 0.f, 0.f, 0.f);
    if (act) {
        float di = dinv[i];
        GATHER8H(hwsB);
        h.x = fmaxf(di * acc.x + bb[sub * 4 + 0], 0.f);
        h.y = fmaxf(di * acc.y + bb[sub * 4 + 1], 0.f);
        h.z = fmaxf(di * acc.z + bb[sub * 4 + 2], 0.f);
        h.w = fmaxf(di * acc.w + bb[sub * 4 + 3], 0.f);
        float p = h.x * w3[sub * 4 + 0] + h.y * w3[sub * 4 + 1]
                + h.z * w3[sub * 4 + 2] + h.w * w3[sub * 4 + 3];
        p += __shfl_xor(p, 1);
        p += __shfl_xor(p, 2);
        if (sub == 0) hws3[i] = di * p;
    }
    float4 hp = h;
#pragma unroll
    for (int m = 4; m < 64; m <<= 1) {
        hp.x += __shfl_xor(hp.x, m);
        hp.y += __shfl_xor(hp.y, m);
        hp.z += __shfl_xor(hp.z, m);
        hp.w += __shfl_xor(hp.w, m);
    }
    if ((tid & 63) < 4) {
        atomicAdd(&lp[sub * 4 + 0], hp.x);
        atomicAdd(&lp[sub * 4 + 1], hp.y);
        atomicAdd(&lp[sub * 4 + 2], hp.z);
        atomicAdd(&lp[sub * 4 + 3], hp.w);
    }
    __syncthreads();
    if (tid < 16) atomicAdd(&pool[tid], lp[tid]);
}

// layer-3 aggregate -> logits c[n]; block max -> one encoded atomicMax
__global__ void __launch_bounds__(BLK) k_agg3(const float* __restrict__ hws3,
                                              const int* __restrict__ offs,
                                              const int* __restrict__ degi,
                                              const int* __restrict__ srcs,
                                              const float* __restrict__ dinv,
                                              const int* __restrict__ perm,
                                              const float* __restrict__ b3,
                                              const int* __restrict__ choices,
                                              float* __restrict__ cbuf,
                                              unsigned* __restrict__ menc, int n) {
    __shared__ float red[BLK];
    int tid = threadIdx.x;
    int nl = tid >> 2, sub = tid & 3;
    int i = perm[blockIdx.x * 64 + nl];
    bool act = (i >= 0);
    float s = 0.f;
    if (act) {
        int beg = offs[i], end = beg + degi[i];
        int j = beg + sub;
        float s1 = 0.f;
        for (; j + 4 < end; j += 8) {
            float q0 = hws3[srcs[j]];
            float q1 = hws3[srcs[j + 4]];
            s += q0; s1 += q1;
        }
        if (j < end) s += hws3[srcs[j]];
        s += s1;
    }
    s += __shfl_xor(s, 1);
    s += __shfl_xor(s, 2);
    float logit = -INFINITY;
    if (act && sub == 0) {
        float c = dinv[i] * (s + 2.f * hws3[i]) + b3[0];
        cbuf[i] = c;
        if (choices[i] != 0) logit = c;
    }
    red[tid] = logit;
    __syncthreads();
    for (int d = BLK / 2; d > 0; d >>= 1) {
        if (tid < d) red[tid] = fmaxf(red[tid], red[tid + d]);
        __syncthreads();
    }
    if (tid == 0) atomicMax(menc, encf(red[0]));
}

__global__ void __launch_bounds__(BLK) k_sumexp(const float* __restrict__ cbuf,
                                                const int* __restrict__ choices,
                                                const unsigned* __restrict__ menc,
                                                float* __restrict__ Ssum, int n) {
    __shared__ float red[BLK];
    int i = blockIdx.x * BLK + threadIdx.x;
    float m = decf(*menc);
    float v = 0.0f;
    if (i < n && choices[i] != 0) v = expf(cbuf[i] - m);
    red[threadIdx.x] = v;
    __syncthreads();
    for (int d = BLK / 2; d > 0; d >>= 1) {
        if (threadIdx.x < d) red[threadIdx.x] += red[threadIdx.x + d];
        __syncthreads();
    }
    if (threadIdx.x == 0) atomicAdd(Ssum, red[0]);
}

__global__ void __launch_bounds__(BLK) k_final(const float* __restrict__ cbuf,
                                               const int* __restrict__ choices,
                                               const unsigned* __restrict__ menc,
                                               const float* __restrict__ Ssum,
                                               const float* __restrict__ pool,
                                               const float* __restrict__ fcw,
                                               const float* __restrict__ fcb,
                                               float* __restrict__ out, int n) {
    int i = blockIdx.x * BLK + threadIdx.x;
    if (i < n) {
        float p = 0.0f;
        if (choices[i] != 0) {
            float m = decf(*menc), S = Ssum[0];
            p = expf(cbuf[i] - m) / S;
        }
        out[i] = p;
    }
    if (blockIdx.x == 0 && threadIdx.x == 0) {
        float invn = 1.0f / (float)n;
        float v = 0.0f;
#pragma unroll
        for (int f = 0; f < 16; f++) v += (pool[f] * invn) * fcw[f];
        out[n] = v + fcb[0];
    }
}

extern "C" void kernel_launch(void* const* d_in, const int* in_sizes, int n_in,
                              void* d_out, int out_size, void* d_ws, size_t ws_size,
                              hipStream_t stream) {
    const float* x       = (const float*)d_in[0];
    const int*   ei      = (const int*)d_in[1];
    const int*   choices = (const int*)d_in[2];
    const float* W1 = (const float*)d_in[3];
    const float* b1 = (const float*)d_in[4];
    const float* W2 = (const float*)d_in[5];
    const float* b2 = (const float*)d_in[6];
    const float* W3 = (const float*)d_in[7];
    const float* b3 = (const float*)d_in[8];
    const float* fcw = (const float*)d_in[9];
    const float* fcb = (const float*)d_in[10];
    float* out = (float*)d_out;

    int n = in_sizes[0] / 3;
    int E = in_sizes[1] / 2;
    const int* row = ei;
    const int* col = ei + E;

    int nblkN = (n + BLK - 1) / BLK;           // 391
    int nbuck = (n + (1 << BSH) - 1) >> BSH;   // 391 buckets of 256 nodes
    int nblkP = nbuck * 4;                     // 1564 (64 perm slots per block)
    int nblkBin = (E + EB - 1) / EB;           // 391 binning blocks

    // workspace layout (16B aligned slices)
    char* ws = (char*)d_ws;
    size_t o = 0;
    auto alloc = [&](size_t bytes) { char* p = ws + o; o += (bytes + 15) & ~(size_t)15; return p; };
    int*   degi   = (int*)  alloc((size_t)n * 4);
    int*   offs   = (int*)  alloc((size_t)n * 4);
    float* dinv   = (float*)alloc((size_t)n * 4);
    float* hws3   = (float*)alloc((size_t)n * 4);
    float* cbuf   = (float*)alloc((size_t)n * 4);
    int*   perm   = (int*)  alloc((size_t)nbuck * 256 * 4);
    int*   gcur   = (int*)  alloc(NB * 4);
    float* scal   = (float*)alloc(256);   // [0]=S, [1..16]=pool, [17]=maxenc
    float* Ssum   = scal + 0;
    float* pool   = scal + 1;
    unsigned* menc = (unsigned*)(scal + 17);
    __half* xs    = (__half*)alloc((size_t)n * 4 * 2);   // half4 per node
    size_t hw_bytes = (size_t)n * 16 * 2;                // hwsB (fp16)
    size_t pk_bytes = (size_t)NB * CAP * 4;              // packed (capacity layout)
    char*  blob   = alloc(hw_bytes > pk_bytes ? hw_bytes : pk_bytes);
    int*    packed = (int*)blob;          // build phase only; dead before k_agg1
    __half* hwsB   = (__half*)blob;
    int*   srcs   = (int*)  alloc((size_t)E * 4);        // tight CSR
    (void)ws_size;  // ~38 MB used

    // ---- build (2 passes over edges; no per-edge global atomics) ----
    k_init<<<1, NB, 0, stream>>>(gcur, scal);
    k_bin<<<nblkBin, BINTH, 0, stream>>>(row, col, gcur, packed, E);
    k_place<<<nbuck, BLK, 0, stream>>>(packed, gcur, x, degi, offs, dinv, xs, srcs, perm, n);

    // ---- GCN layers (degree-sorted processing order via perm) ----
    k_agg1<<<nblkP, BLK, 0, stream>>>(xs, offs, degi, srcs, dinv, perm, b1, W1, W2, hwsB, n);
    k_agg2<<<nblkP, BLK, 0, stream>>>(hwsB, offs, degi, srcs, dinv, perm, b2, W3, hws3, pool, n);
    k_agg3<<<nblkP, BLK, 0, stream>>>(hws3, offs, degi, srcs, dinv, perm, b3, choices, cbuf, menc, n);

    // ---- softmax + value head ----
    k_sumexp<<<nblkN, BLK, 0, stream>>>(cbuf, choices, menc, Ssum, n);
    k_final<<<nblkN, BLK, 0, stream>>>(cbuf, choices, menc, Ssum, pool, fcw, fcb, out, n);
}

// Round 11
// 232.797 us; speedup vs baseline: 1.1286x; 1.1286x over previous
//
#include <hip/hip_runtime.h>
#include <hip/hip_fp16.h>
#include <math.h>

#define BLK 256

// ---------------------------------------------------------------------------
// GCNPolicyNetwork: 3-layer improved-GCN + masked softmax + mean-pool value.
// Round 11: perm REVERTED (R10: degree-sort scattered srcs/write locality,
// FETCH 33->49MB, regressed; linear node order is itself an optimization).
// New: (1) padded vectorized srcs: per-node source lists padded to x4 with a
// dummy node n (zero payload) in a per-bucket capacity layout -> all gather
// loops use int4 index loads, no remainder divergence, k_place loses its
// cross-bucket prefix pass. (2) softmax fused: k_agg3 emits per-block
// (max, sum-exp); 1-block k_comb combines; k_sumexp deleted.
// Gather structure: R9's node-centric 4-lane fp16, unroll x8 (best known).
// ---------------------------------------------------------------------------

#define BSH 8                    // 256 nodes per bucket
#define NB 512                   // bucket-array size (nbuck=391 <= 512)
#define CAP 10240                // packed[] capacity per bucket (mean ~8184)
#define SCAP 11264               // srcs[] capacity per bucket (CAP + 4*256 pad)
#define EB 8192                  // edges per binning block
#define BINTH 512                // k_bin block size

// ---- fp16 payload helpers ----
__device__ inline float4 load_h4(const __half* base, int node, int sub) {
    const uint2* p = reinterpret_cast<const uint2*>(base + ((size_t)node << 4)) + sub;
    uint2 u = *p;
    union { unsigned u; __half2 h; } a, b;
    a.u = u.x; b.u = u.y;
    float2 fa = __half22float2(a.h), fb = __half22float2(b.h);
    return make_float4(fa.x, fa.y, fb.x, fb.y);
}

__device__ inline void store_h4(__half* base, int node, int sub, float4 v) {
    union { unsigned u; __half2 h; } a, b;
    a.h = __floats2half2_rn(v.x, v.y);
    b.h = __floats2half2_rn(v.z, v.w);
    uint2 u; u.x = a.u; u.y = b.u;
    *(reinterpret_cast<uint2*>(base + ((size_t)node << 4)) + sub) = u;
}

// xs payload: half4 (dinv*x0, dinv*x1, dinv*x2, 0) = 8 B per node
__device__ inline float3 load_xs(const __half* xs, int node) {
    uint2 u = *reinterpret_cast<const uint2*>(xs + ((size_t)node << 2));
    union { unsigned u; __half2 h; } a, b;
    a.u = u.x; b.u = u.y;
    float2 fa = __half22float2(a.h), fb = __half22float2(b.h);
    return make_float3(fa.x, fa.y, fb.x);
}

// zero gcur[NB] + scal[18] (Ssum, pool[16], scal_m)
__global__ void k_init(int* __restrict__ gcur, float* __restrict__ scal) {
    int t = threadIdx.x;
    gcur[t] = 0;
    if (t < 18) scal[t] = 0.f;
}

// LDS multisplit of edges into 256-node buckets; reserve directly in the
// fixed-capacity packed[] layout (bucket b owns [b*CAP, b*CAP+cnt)).
__global__ void __launch_bounds__(BINTH) k_bin(const int* __restrict__ row,
                                               const int* __restrict__ col,
                                               int* __restrict__ gcur,
                                               int* __restrict__ packed, int E) {
    __shared__ int stage[EB];
    __shared__ unsigned short sbuk[EB];
    __shared__ int hist[NB];
    __shared__ int lscan[NB];
    __shared__ int cur[NB];
    __shared__ int gbase[NB];
    int tid = threadIdx.x;
    int base = blockIdx.x * EB;
    int cnt = min(EB, E - base);

    hist[tid] = 0;
    __syncthreads();
    for (int j = tid; j < cnt; j += BINTH) {
        int c = __builtin_nontemporal_load(col + base + j);
        atomicAdd(&hist[c >> BSH], 1);
    }
    __syncthreads();
    lscan[tid] = hist[tid];
    __syncthreads();
    for (int d = 1; d < NB; d <<= 1) {
        int t = (tid >= d) ? lscan[tid - d] : 0;
        __syncthreads();
        if (tid >= d) lscan[tid] += t;
        __syncthreads();
    }
    {
        int ex = lscan[tid] - hist[tid];
        lscan[tid] = ex;
        cur[tid] = ex;
    }
    __syncthreads();
    for (int j = tid; j < cnt; j += BINTH) {
        int c = __builtin_nontemporal_load(col + base + j);
        int r = __builtin_nontemporal_load(row + base + j);
        int b = c >> BSH;
        int p = atomicAdd(&cur[b], 1);
        stage[p] = (r << BSH) | (c & ((1 << BSH) - 1));
        sbuk[p] = (unsigned short)b;
    }
    __syncthreads();
    if (hist[tid] > 0) gbase[tid] = tid * CAP + atomicAdd(&gcur[tid], hist[tid]);
    __syncthreads();
    for (int j = tid; j < cnt; j += BINTH) {
        int b = sbuk[j];
        int pos = gbase[b] + (j - lscan[b]);
        packed[pos] = stage[j];
    }
}

// per-bucket: degree hist + scan of PADDED lengths -> degi(padded)/offs/dinv/xs,
// dummy-pad fill, then fine placement into srcs (capacity layout, x4-aligned).
__global__ void __launch_bounds__(BLK) k_place(const int* __restrict__ packed,
                                               const int* __restrict__ bcnt,
                                               const float* __restrict__ x,
                                               int* __restrict__ degi,
                                               int* __restrict__ offs,
                                               float* __restrict__ dinv,
                                               __half* __restrict__ xs,
                                               int* __restrict__ srcs, int n) {
    __shared__ int cnt[256];
    __shared__ int lcur[256];
    __shared__ int ssum[256];
    int tid = threadIdx.x;
    int b = blockIdx.x;
    int nb0 = b << BSH;
    cnt[tid] = 0;
    __syncthreads();
    int ecnt = bcnt[b];
    const int* pk = packed + (size_t)b * CAP;
    for (int j = tid; j < ecnt; j += BLK)
        atomicAdd(&cnt[pk[j] & 255], 1);
    __syncthreads();
    int c = cnt[tid];
    int pl = (c + 3) & ~3;                 // padded length (x4)
    ssum[tid] = pl;
    __syncthreads();
    for (int d = 1; d < 256; d <<= 1) {
        int t = (tid >= d) ? ssum[tid - d] : 0;
        __syncthreads();
        if (tid >= d) ssum[tid] += t;
        __syncthreads();
    }
    int A = b * SCAP + (ssum[tid] - pl);   // absolute aligned base for node
    lcur[tid] = A;
    int valid = min(n - nb0, 256);
    int i = nb0 + tid;
    if (tid < valid) {
        degi[i] = pl;
        offs[i] = A;
        float di = rsqrtf((float)c + 2.0f);
        dinv[i] = di;
        float x0 = x[i * 3 + 0], x1 = x[i * 3 + 1], x2 = x[i * 3 + 2];
        union { unsigned u; __half2 h; } a2, b2;
        a2.h = __floats2half2_rn(di * x0, di * x1);
        b2.h = __floats2half2_rn(di * x2, 0.f);
        uint2 u; u.x = a2.u; u.y = b2.u;
        *reinterpret_cast<uint2*>(xs + ((size_t)i << 2)) = u;
        for (int k = c; k < pl; k++) srcs[A + k] = n;   // dummy pads
    }
    if (b == 0 && tid == 0) {              // zero the dummy xs payload
        uint2 z; z.x = 0u; z.y = 0u;
        *reinterpret_cast<uint2*>(xs + ((size_t)n << 2)) = z;
    }
    __syncthreads();
    for (int j = tid; j < ecnt; j += BLK) {
        int v = pk[j];
        int li = v & 255;
        int slot = atomicAdd(&lcur[li], 1);
        srcs[slot] = v >> BSH;
    }
}

// layer-1: rank-3 aggregation of xs, then @W1 + relu, then @W2 -> hwsB (fp16).
// Lane sub walks int4 chunks at A+4*sub stride 16 (covers all: pc % 4 == 0).
__global__ void __launch_bounds__(BLK) k_agg1(const __half* __restrict__ xs,
                                              const int* __restrict__ offs,
                                              const int* __restrict__ degi,
                                              const int* __restrict__ srcs,
                                              const float* __restrict__ dinv,
                                              const float* __restrict__ b1,
                                              const float* __restrict__ W1,
                                              const float* __restrict__ W2,
                                              __half* __restrict__ hwsB, int n) {
    __shared__ float w1[48];
    __shared__ float w2[256];
    __shared__ float bb[16];
    __shared__ float hbuf[64][17];
    int tid = threadIdx.x;
    w2[tid] = W2[tid];
    if (tid < 48) w1[tid] = W1[tid];
    if (tid < 16) bb[tid] = b1[tid];
    if (blockIdx.x == 0 && tid < 8)        // zero the dummy hwsB payload (32 B)
        reinterpret_cast<unsigned*>(hwsB + ((size_t)n << 4))[tid] = 0u;
    __syncthreads();
    int nl = tid >> 2, sub = tid & 3;
    int i = blockIdx.x * 64 + nl;
    bool act = (i < n);
    float di = 0.f;
    if (act) {
        di = dinv[i];
        float ax = 0.f, ay = 0.f, az = 0.f;
        float bx = 0.f, by = 0.f, bz = 0.f;
        int A = offs[i], pc = degi[i];
        for (int j = A + 4 * sub; j < A + pc; j += 16) {
            int4 s = *reinterpret_cast<const int4*>(srcs + j);
            float3 q0 = load_xs(xs, s.x);
            float3 q1 = load_xs(xs, s.y);
            float3 q2 = load_xs(xs, s.z);
            float3 q3 = load_xs(xs, s.w);
            ax += q0.x + q1.x; ay += q0.y + q1.y; az += q0.z + q1.z;
            bx += q2.x + q3.x; by += q2.y + q3.y; bz += q2.z + q3.z;
        }
        ax += bx; ay += by; az += bz;
        ax += __shfl_xor(ax, 1); ay += __shfl_xor(ay, 1); az += __shfl_xor(az, 1);
        ax += __shfl_xor(ax, 2); ay += __shfl_xor(ay, 2); az += __shfl_xor(az, 2);
        float3 s = load_xs(xs, i);
        ax += 2.f * s.x; ay += 2.f * s.y; az += 2.f * s.z;
#pragma unroll
        for (int k = 0; k < 4; k++) {
            int f = sub * 4 + k;
            float hv = di * (ax * w1[f] + ay * w1[16 + f] + az * w1[32 + f]) + bb[f];
            hbuf[nl][f] = fmaxf(hv, 0.f);
        }
    }
    __syncthreads();
    if (act) {
        const float* hn = hbuf[nl];
        float s0 = 0.f, s1 = 0.f, s2 = 0.f, s3 = 0.f;
#pragma unroll
        for (int f = 0; f < 16; f++) {
            float hv = hn[f];
            const float4 wq = *(const float4*)&w2[f * 16 + sub * 4];
            s0 += hv * wq.x; s1 += hv * wq.y; s2 += hv * wq.z; s3 += hv * wq.w;
        }
        store_h4(hwsB, i, sub, make_float4(di * s0, di * s1, di * s2, di * s3));
    }
}

// node-centric 4-lane gather, fp16 payload, int4 index loads, no tail divergence
#define GATHERV(HWS)                                                            \
    float4 acc;                                                                 \
    {                                                                           \
        float4 s0 = load_h4(HWS, i, sub);                                       \
        acc = make_float4(2.f * s0.x, 2.f * s0.y, 2.f * s0.z, 2.f * s0.w);      \
        float4 a1 = make_float4(0.f, 0.f, 0.f, 0.f);                            \
        float4 a2 = a1, a3 = a1;                                                \
        int A = offs[i], pc = degi[i];                                          \
        int j = A;                                                              \
        for (; j + 8 <= A + pc; j += 8) {                                       \
            int4 sa = *reinterpret_cast<const int4*>(srcs + j);                 \
            int4 sb = *reinterpret_cast<const int4*>(srcs + j + 4);             \
            float4 q0 = load_h4(HWS, sa.x, sub);                                \
            float4 q1 = load_h4(HWS, sa.y, sub);                                \
            float4 q2 = load_h4(HWS, sa.z, sub);                                \
            float4 q3 = load_h4(HWS, sa.w, sub);                                \
            float4 q4 = load_h4(HWS, sb.x, sub);                                \
            float4 q5 = load_h4(HWS, sb.y, sub);                                \
            float4 q6 = load_h4(HWS, sb.z, sub);                                \
            float4 q7 = load_h4(HWS, sb.w, sub);                                \
            acc.x += q0.x + q4.x; acc.y += q0.y + q4.y;                         \
            acc.z += q0.z + q4.z; acc.w += q0.w + q4.w;                         \
            a1.x += q1.x + q5.x; a1.y += q1.y + q5.y;                           \
            a1.z += q1.z + q5.z; a1.w += q1.w + q5.w;                           \
            a2.x += q2.x + q6.x; a2.y += q2.y + q6.y;                           \
            a2.z += q2.z + q6.z; a2.w += q2.w + q6.w;                           \
            a3.x += q3.x + q7.x; a3.y += q3.y + q7.y;                           \
            a3.z += q3.z + q7.z; a3.w += q3.w + q7.w;                           \
        }                                                                       \
        if (j < A + pc) {                  /* exactly 4 remain (pc % 8 == 4) */ \
            int4 sa = *reinterpret_cast<const int4*>(srcs + j);                 \
            float4 q0 = load_h4(HWS, sa.x, sub);                                \
            float4 q1 = load_h4(HWS, sa.y, sub);                                \
            float4 q2 = load_h4(HWS, sa.z, sub);                                \
            float4 q3 = load_h4(HWS, sa.w, sub);                                \
            acc.x += q0.x; acc.y += q0.y; acc.z += q0.z; acc.w += q0.w;         \
            a1.x += q1.x; a1.y += q1.y; a1.z += q1.z; a1.w += q1.w;             \
            a2.x += q2.x; a2.y += q2.y; a2.z += q2.z; a2.w += q2.w;             \
            a3.x += q3.x; a3.y += q3.y; a3.z += q3.z; a3.w += q3.w;             \
        }                                                                       \
        acc.x += a1.x + a2.x + a3.x;                                            \
        acc.y += a1.y + a2.y + a3.y;                                            \
        acc.z += a1.z + a2.z + a3.z;                                            \
        acc.w += a1.w + a2.w + a3.w;                                            \
    }

// layer-2 aggregate + relu (-> h2), pool accumulation, layer-3 transform
__global__ void __launch_bounds__(BLK) k_agg2(const __half* __restrict__ hwsB,
                                              const int* __restrict__ offs,
                                              const int* __restrict__ degi,
                                              const int* __restrict__ srcs,
                                              const float* __restrict__ dinv,
                                              const float* __restrict__ b2,
                                              const float* __restrict__ W3,
                                              float* __restrict__ hws3,
                                              float* __restrict__ pool, int n) {
    __shared__ float w3[16];
    __shared__ float bb[16];
    __shared__ float lp[16];
    int tid = threadIdx.x;
    if (tid < 16) { w3[tid] = W3[tid]; bb[tid] = b2[tid]; lp[tid] = 0.f; }
    if (blockIdx.x == 0 && tid == 0) hws3[n] = 0.f;   // zero dummy hws3
    __syncthreads();
    int nl = tid >> 2, sub = tid & 3;
    int i = blockIdx.x * 64 + nl;
    bool act = (i < n);
    float4 h = make_float4(0.f, 0.f, 0.f, 0.f);
    if (act) {
        float di = dinv[i];
        GATHERV(hwsB);
        h.x = fmaxf(di * acc.x + bb[sub * 4 + 0], 0.f);
        h.y = fmaxf(di * acc.y + bb[sub * 4 + 1], 0.f);
        h.z = fmaxf(di * acc.z + bb[sub * 4 + 2], 0.f);
        h.w = fmaxf(di * acc.w + bb[sub * 4 + 3], 0.f);
        float p = h.x * w3[sub * 4 + 0] + h.y * w3[sub * 4 + 1]
                + h.z * w3[sub * 4 + 2] + h.w * w3[sub * 4 + 3];
        p += __shfl_xor(p, 1);
        p += __shfl_xor(p, 2);
        if (sub == 0) hws3[i] = di * p;
    }
    float4 hp = h;
#pragma unroll
    for (int m = 4; m < 64; m <<= 1) {
        hp.x += __shfl_xor(hp.x, m);
        hp.y += __shfl_xor(hp.y, m);
        hp.z += __shfl_xor(hp.z, m);
        hp.w += __shfl_xor(hp.w, m);
    }
    if ((tid & 63) < 4) {
        atomicAdd(&lp[sub * 4 + 0], hp.x);
        atomicAdd(&lp[sub * 4 + 1], hp.y);
        atomicAdd(&lp[sub * 4 + 2], hp.z);
        atomicAdd(&lp[sub * 4 + 3], hp.w);
    }
    __syncthreads();
    if (tid < 16) atomicAdd(&pool[tid], lp[tid]);
}

// layer-3 aggregate -> logits; per-block (max, sum-exp) for fused softmax
__global__ void __launch_bounds__(BLK) k_agg3(const float* __restrict__ hws3,
                                              const int* __restrict__ offs,
                                              const int* __restrict__ degi,
                                              const int* __restrict__ srcs,
                                              const float* __restrict__ dinv,
                                              const float* __restrict__ b3,
                                              const int* __restrict__ choices,
                                              float* __restrict__ cbuf,
                                              float* __restrict__ bmax,
                                              float* __restrict__ bsum, int n) {
    __shared__ float red[BLK];
    int tid = threadIdx.x;
    int nl = tid >> 2, sub = tid & 3;
    int i = blockIdx.x * 64 + nl;
    bool act = (i < n);
    float s0 = 0.f, s1 = 0.f;
    if (act) {
        int A = offs[i], pc = degi[i];
        for (int j = A + 4 * sub; j < A + pc; j += 16) {
            int4 s = *reinterpret_cast<const int4*>(srcs + j);
            s0 += hws3[s.x] + hws3[s.z];
            s1 += hws3[s.y] + hws3[s.w];
        }
    }
    float s = s0 + s1;
    s += __shfl_xor(s, 1);
    s += __shfl_xor(s, 2);
    float logit = -INFINITY;
    if (act && sub == 0) {
        float c = dinv[i] * (s + 2.f * hws3[i]) + b3[0];
        cbuf[i] = c;
        if (choices[i] != 0) logit = c;
    }
    red[tid] = logit;
    __syncthreads();
    for (int d = BLK / 2; d > 0; d >>= 1) {
        if (tid < d) red[tid] = fmaxf(red[tid], red[tid + d]);
        __syncthreads();
    }
    float bm = red[0];
    __syncthreads();
    red[tid] = (logit > -INFINITY) ? expf(logit - bm) : 0.f;
    __syncthreads();
    for (int d = BLK / 2; d > 0; d >>= 1) {
        if (tid < d) red[tid] += red[tid + d];
        __syncthreads();
    }
    if (tid == 0) { bmax[blockIdx.x] = bm; bsum[blockIdx.x] = red[0]; }
}

// combine per-block (max, sum) -> global (M, S)
__global__ void __launch_bounds__(BLK) k_comb(const float* __restrict__ bmax,
                                              const float* __restrict__ bsum,
                                              float* __restrict__ scal_m,
                                              float* __restrict__ Ssum, int nblk) {
    __shared__ float red[BLK];
    int tid = threadIdx.x;
    float m = -INFINITY;
    for (int i = tid; i < nblk; i += BLK) m = fmaxf(m, bmax[i]);
    red[tid] = m;
    __syncthreads();
    for (int d = BLK / 2; d > 0; d >>= 1) {
        if (tid < d) red[tid] = fmaxf(red[tid], red[tid + d]);
        __syncthreads();
    }
    float M = red[0];
    __syncthreads();
    float s = 0.f;
    for (int i = tid; i < nblk; i += BLK) {
        float bm = bmax[i];
        if (bm > -INFINITY) s += bsum[i] * expf(bm - M);
    }
    red[tid] = s;
    __syncthreads();
    for (int d = BLK / 2; d > 0; d >>= 1) {
        if (tid < d) red[tid] += red[tid + d];
        __syncthreads();
    }
    if (tid == 0) { scal_m[0] = M; Ssum[0] = red[0]; }
}

__global__ void __launch_bounds__(BLK) k_final(const float* __restrict__ cbuf,
                                               const int* __restrict__ choices,
                                               const float* __restrict__ scal_m,
                                               const float* __restrict__ Ssum,
                                               const float* __restrict__ pool,
                                               const float* __restrict__ fcw,
                                               const float* __restrict__ fcb,
                                               float* __restrict__ out, int n) {
    int i = blockIdx.x * BLK + threadIdx.x;
    if (i < n) {
        float p = 0.0f;
        if (choices[i] != 0) {
            float m = scal_m[0], S = Ssum[0];
            p = expf(cbuf[i] - m) / S;
        }
        out[i] = p;
    }
    if (blockIdx.x == 0 && threadIdx.x == 0) {
        float invn = 1.0f / (float)n;
        float v = 0.0f;
#pragma unroll
        for (int f = 0; f < 16; f++) v += (pool[f] * invn) * fcw[f];
        out[n] = v + fcb[0];
    }
}

extern "C" void kernel_launch(void* const* d_in, const int* in_sizes, int n_in,
                              void* d_out, int out_size, void* d_ws, size_t ws_size,
                              hipStream_t stream) {
    const float* x       = (const float*)d_in[0];
    const int*   ei      = (const int*)d_in[1];
    const int*   choices = (const int*)d_in[2];
    const float* W1 = (const float*)d_in[3];
    const float* b1 = (const float*)d_in[4];
    const float* W2 = (const float*)d_in[5];
    const float* b2 = (const float*)d_in[6];
    const float* W3 = (const float*)d_in[7];
    const float* b3 = (const float*)d_in[8];
    const float* fcw = (const float*)d_in[9];
    const float* fcb = (const float*)d_in[10];
    float* out = (float*)d_out;

    int n = in_sizes[0] / 3;
    int E = in_sizes[1] / 2;
    const int* row = ei;
    const int* col = ei + E;

    int nblkN = (n + BLK - 1) / BLK;           // 391
    int nblk64 = (n + 63) / 64;                // 1563
    int nbuck = (n + (1 << BSH) - 1) >> BSH;   // 391 buckets of 256 nodes
    int nblkBin = (E + EB - 1) / EB;           // 391 binning blocks

    // workspace layout (16B aligned slices); ws_size is ~268 MB, plenty
    char* ws = (char*)d_ws;
    size_t o = 0;
    auto alloc = [&](size_t bytes) { char* p = ws + o; o += (bytes + 15) & ~(size_t)15; return p; };
    int*   degi   = (int*)  alloc((size_t)n * 4);
    int*   offs   = (int*)  alloc((size_t)n * 4);
    float* dinv   = (float*)alloc((size_t)n * 4);
    float* hws3   = (float*)alloc((size_t)(n + 1) * 4);  // +1: dummy node
    float* cbuf   = (float*)alloc((size_t)n * 4);
    float* bmax   = (float*)alloc(8192);       // >= nblk64 floats
    float* bsum   = (float*)alloc(8192);
    int*   gcur   = (int*)  alloc(NB * 4);
    float* scal   = (float*)alloc(256);   // [0]=S, [1..16]=pool, [17]=m
    float* Ssum   = scal + 0;
    float* pool   = scal + 1;
    float* scal_m = scal + 17;
    __half* xs    = (__half*)alloc((size_t)(n + 1) * 4 * 2);  // half4/node +dummy
    size_t hw_bytes = (size_t)(n + 1) * 16 * 2;          // hwsB (fp16) + dummy
    size_t pk_bytes = (size_t)NB * CAP * 4;              // packed (capacity layout)
    char*  blob   = alloc(hw_bytes > pk_bytes ? hw_bytes : pk_bytes);
    int*    packed = (int*)blob;          // build phase only; dead before k_agg1
    __half* hwsB   = (__half*)blob;
    int*   srcs   = (int*)  alloc((size_t)NB * SCAP * 4);    // capacity layout
    (void)ws_size;  // ~60 MB used

    // ---- build (2 passes over edges; no per-edge global atomics) ----
    k_init<<<1, NB, 0, stream>>>(gcur, scal);
    k_bin<<<nblkBin, BINTH, 0, stream>>>(row, col, gcur, packed, E);
    k_place<<<nbuck, BLK, 0, stream>>>(packed, gcur, x, degi, offs, dinv, xs, srcs, n);

    // ---- GCN layers (linear node order; padded vectorized srcs) ----
    k_agg1<<<nblk64, BLK, 0, stream>>>(xs, offs, degi, srcs, dinv, b1, W1, W2, hwsB, n);
    k_agg2<<<nblk64, BLK, 0, stream>>>(hwsB, offs, degi, srcs, dinv, b2, W3, hws3, pool, n);
    k_agg3<<<nblk64, BLK, 0, stream>>>(hws3, offs, degi, srcs, dinv, b3, choices, cbuf, bmax, bsum, n);

    // ---- fused softmax combine + outputs ----
    k_comb<<<1, BLK, 0, stream>>>(bmax, bsum, scal_m, Ssum, nblk64);
    k_final<<<nblkN, BLK, 0, stream>>>(cbuf, choices, scal_m, Ssum, pool, fcw, fcb, out, n);
}

// Round 12
// 225.798 us; speedup vs baseline: 1.1636x; 1.0310x over previous
//
#include <hip/hip_runtime.h>
#include <hip/hip_fp16.h>
#include <math.h>

#define BLK 256

// ---------------------------------------------------------------------------
// GCNPolicyNetwork: 3-layer improved-GCN + masked softmax + mean-pool value.
// Round 12: (1) source lists padded to x8 (no gather tail at all);
// (2) DUAL-NODE interleaved gather in k_agg2/k_agg3: each 4-lane team walks
// nodes i and i+64 simultaneously (16 payload loads in flight per step,
// branchless via clamped index loads + dummy-node select, dummy payload = 0);
// (3) k_comb deleted - k_final redundantly combines per-block (max,sumexp).
// Linear node order kept (R10 showed permuting it wrecks srcs locality).
// Build: R9's fixed-capacity multisplit (2 edge passes, no per-edge atomics).
// ---------------------------------------------------------------------------

#define BSH 8                    // 256 nodes per bucket
#define NB 512                   // bucket-array size (nbuck=391 <= 512)
#define CAP 10240                // packed[] capacity per bucket (mean ~8184)
#define SCAP 12288               // srcs[] capacity per bucket (CAP + 8*256 pad)
#define EB 8192                  // edges per binning block
#define BINTH 512                // k_bin block size

// ---- fp16 payload helpers ----
__device__ inline float4 load_h4(const __half* base, int node, int sub) {
    const uint2* p = reinterpret_cast<const uint2*>(base + ((size_t)node << 4)) + sub;
    uint2 u = *p;
    union { unsigned u; __half2 h; } a, b;
    a.u = u.x; b.u = u.y;
    float2 fa = __half22float2(a.h), fb = __half22float2(b.h);
    return make_float4(fa.x, fa.y, fb.x, fb.y);
}

__device__ inline void store_h4(__half* base, int node, int sub, float4 v) {
    union { unsigned u; __half2 h; } a, b;
    a.h = __floats2half2_rn(v.x, v.y);
    b.h = __floats2half2_rn(v.z, v.w);
    uint2 u; u.x = a.u; u.y = b.u;
    *(reinterpret_cast<uint2*>(base + ((size_t)node << 4)) + sub) = u;
}

// xs payload: half4 (dinv*x0, dinv*x1, dinv*x2, 0) = 8 B per node
__device__ inline float3 load_xs(const __half* xs, int node) {
    uint2 u = *reinterpret_cast<const uint2*>(xs + ((size_t)node << 2));
    union { unsigned u; __half2 h; } a, b;
    a.u = u.x; b.u = u.y;
    float2 fa = __half22float2(a.h), fb = __half22float2(b.h);
    return make_float3(fa.x, fa.y, fb.x);
}

// zero gcur[NB] + scal[18] (Ssum, pool[16], scal_m)
__global__ void k_init(int* __restrict__ gcur, float* __restrict__ scal) {
    int t = threadIdx.x;
    gcur[t] = 0;
    if (t < 18) scal[t] = 0.f;
}

// LDS multisplit of edges into 256-node buckets; reserve directly in the
// fixed-capacity packed[] layout (bucket b owns [b*CAP, b*CAP+cnt)).
__global__ void __launch_bounds__(BINTH) k_bin(const int* __restrict__ row,
                                               const int* __restrict__ col,
                                               int* __restrict__ gcur,
                                               int* __restrict__ packed, int E) {
    __shared__ int stage[EB];
    __shared__ unsigned short sbuk[EB];
    __shared__ int hist[NB];
    __shared__ int lscan[NB];
    __shared__ int cur[NB];
    __shared__ int gbase[NB];
    int tid = threadIdx.x;
    int base = blockIdx.x * EB;
    int cnt = min(EB, E - base);

    hist[tid] = 0;
    __syncthreads();
    for (int j = tid; j < cnt; j += BINTH) {
        int c = __builtin_nontemporal_load(col + base + j);
        atomicAdd(&hist[c >> BSH], 1);
    }
    __syncthreads();
    lscan[tid] = hist[tid];
    __syncthreads();
    for (int d = 1; d < NB; d <<= 1) {
        int t = (tid >= d) ? lscan[tid - d] : 0;
        __syncthreads();
        if (tid >= d) lscan[tid] += t;
        __syncthreads();
    }
    {
        int ex = lscan[tid] - hist[tid];
        lscan[tid] = ex;
        cur[tid] = ex;
    }
    __syncthreads();
    for (int j = tid; j < cnt; j += BINTH) {
        int c = __builtin_nontemporal_load(col + base + j);
        int r = __builtin_nontemporal_load(row + base + j);
        int b = c >> BSH;
        int p = atomicAdd(&cur[b], 1);
        stage[p] = (r << BSH) | (c & ((1 << BSH) - 1));
        sbuk[p] = (unsigned short)b;
    }
    __syncthreads();
    if (hist[tid] > 0) gbase[tid] = tid * CAP + atomicAdd(&gcur[tid], hist[tid]);
    __syncthreads();
    for (int j = tid; j < cnt; j += BINTH) {
        int b = sbuk[j];
        int pos = gbase[b] + (j - lscan[b]);
        packed[pos] = stage[j];
    }
}

// per-bucket: degree hist + scan of PADDED(x8) lengths -> degi/offs/dinv/xs,
// dummy-pad fill, then fine placement into srcs (capacity layout, x8-aligned).
__global__ void __launch_bounds__(BLK) k_place(const int* __restrict__ packed,
                                               const int* __restrict__ bcnt,
                                               const float* __restrict__ x,
                                               int* __restrict__ degi,
                                               int* __restrict__ offs,
                                               float* __restrict__ dinv,
                                               __half* __restrict__ xs,
                                               int* __restrict__ srcs, int n) {
    __shared__ int cnt[256];
    __shared__ int lcur[256];
    __shared__ int ssum[256];
    int tid = threadIdx.x;
    int b = blockIdx.x;
    int nb0 = b << BSH;
    cnt[tid] = 0;
    __syncthreads();
    int ecnt = bcnt[b];
    const int* pk = packed + (size_t)b * CAP;
    for (int j = tid; j < ecnt; j += BLK)
        atomicAdd(&cnt[pk[j] & 255], 1);
    __syncthreads();
    int c = cnt[tid];
    int pl = (c + 7) & ~7;                 // padded length (x8)
    ssum[tid] = pl;
    __syncthreads();
    for (int d = 1; d < 256; d <<= 1) {
        int t = (tid >= d) ? ssum[tid - d] : 0;
        __syncthreads();
        if (tid >= d) ssum[tid] += t;
        __syncthreads();
    }
    int A = b * SCAP + (ssum[tid] - pl);   // absolute aligned base for node
    lcur[tid] = A;
    int valid = min(n - nb0, 256);
    int i = nb0 + tid;
    if (tid < valid) {
        degi[i] = pl;
        offs[i] = A;
        float di = rsqrtf((float)c + 2.0f);
        dinv[i] = di;
        float x0 = x[i * 3 + 0], x1 = x[i * 3 + 1], x2 = x[i * 3 + 2];
        union { unsigned u; __half2 h; } a2, b2;
        a2.h = __floats2half2_rn(di * x0, di * x1);
        b2.h = __floats2half2_rn(di * x2, 0.f);
        uint2 u; u.x = a2.u; u.y = b2.u;
        *reinterpret_cast<uint2*>(xs + ((size_t)i << 2)) = u;
        for (int k = c; k < pl; k++) srcs[A + k] = n;   // dummy pads
    }
    if (b == 0 && tid == 0) {              // zero the dummy xs payload
        uint2 z; z.x = 0u; z.y = 0u;
        *reinterpret_cast<uint2*>(xs + ((size_t)n << 2)) = z;
    }
    __syncthreads();
    for (int j = tid; j < ecnt; j += BLK) {
        int v = pk[j];
        int li = v & 255;
        int slot = atomicAdd(&lcur[li], 1);
        srcs[slot] = v >> BSH;
    }
}

// layer-1: rank-3 aggregation of xs, then @W1 + relu, then @W2 -> hwsB (fp16).
// Lane sub walks int4 chunks at A+4*sub stride 16 (pl % 4 == 0 covers all).
__global__ void __launch_bounds__(BLK) k_agg1(const __half* __restrict__ xs,
                                              const int* __restrict__ offs,
                                              const int* __restrict__ degi,
                                              const int* __restrict__ srcs,
                                              const float* __restrict__ dinv,
                                              const float* __restrict__ b1,
                                              const float* __restrict__ W1,
                                              const float* __restrict__ W2,
                                              __half* __restrict__ hwsB, int n) {
    __shared__ float w1[48];
    __shared__ float w2[256];
    __shared__ float bb[16];
    __shared__ float hbuf[64][17];
    int tid = threadIdx.x;
    w2[tid] = W2[tid];
    if (tid < 48) w1[tid] = W1[tid];
    if (tid < 16) bb[tid] = b1[tid];
    if (blockIdx.x == 0 && tid < 8)        // zero the dummy hwsB payload (32 B)
        reinterpret_cast<unsigned*>(hwsB + ((size_t)n << 4))[tid] = 0u;
    __syncthreads();
    int nl = tid >> 2, sub = tid & 3;
    int i = blockIdx.x * 64 + nl;
    bool act = (i < n);
    float di = 0.f;
    if (act) {
        di = dinv[i];
        float ax = 0.f, ay = 0.f, az = 0.f;
        float bx = 0.f, by = 0.f, bz = 0.f;
        int A = offs[i], pc = degi[i];
        for (int j = A + 4 * sub; j < A + pc; j += 16) {
            int4 s = *reinterpret_cast<const int4*>(srcs + j);
            float3 q0 = load_xs(xs, s.x);
            float3 q1 = load_xs(xs, s.y);
            float3 q2 = load_xs(xs, s.z);
            float3 q3 = load_xs(xs, s.w);
            ax += q0.x + q1.x; ay += q0.y + q1.y; az += q0.z + q1.z;
            bx += q2.x + q3.x; by += q2.y + q3.y; bz += q2.z + q3.z;
        }
        ax += bx; ay += by; az += bz;
        ax += __shfl_xor(ax, 1); ay += __shfl_xor(ay, 1); az += __shfl_xor(az, 1);
        ax += __shfl_xor(ax, 2); ay += __shfl_xor(ay, 2); az += __shfl_xor(az, 2);
        float3 s = load_xs(xs, i);
        ax += 2.f * s.x; ay += 2.f * s.y; az += 2.f * s.z;
#pragma unroll
        for (int k = 0; k < 4; k++) {
            int f = sub * 4 + k;
            float hv = di * (ax * w1[f] + ay * w1[16 + f] + az * w1[32 + f]) + bb[f];
            hbuf[nl][f] = fmaxf(hv, 0.f);
        }
    }
    __syncthreads();
    if (act) {
        const float* hn = hbuf[nl];
        float s0 = 0.f, s1 = 0.f, s2 = 0.f, s3 = 0.f;
#pragma unroll
        for (int f = 0; f < 16; f++) {
            float hv = hn[f];
            const float4 wq = *(const float4*)&w2[f * 16 + sub * 4];
            s0 += hv * wq.x; s1 += hv * wq.y; s2 += hv * wq.z; s3 += hv * wq.w;
        }
        store_h4(hwsB, i, sub, make_float4(di * s0, di * s1, di * s2, di * s3));
    }
}

// layer-2: DUAL-NODE interleaved gather + relu + pool + layer-3 transform.
// Team of 4 lanes walks nodes iA and iB=iA+64 together; exhausted stream
// reads clamped address and selects dummy node n (payload 0). 128 nodes/block.
__global__ void __launch_bounds__(BLK) k_agg2(const __half* __restrict__ hwsB,
                                              const int* __restrict__ offs,
                                              const int* __restrict__ degi,
                                              const int* __restrict__ srcs,
                                              const float* __restrict__ dinv,
                                              const float* __restrict__ b2,
                                              const float* __restrict__ W3,
                                              float* __restrict__ hws3,
                                              float* __restrict__ pool, int n) {
    __shared__ float w3[16];
    __shared__ float bb[16];
    __shared__ float lp[16];
    int tid = threadIdx.x;
    if (tid < 16) { w3[tid] = W3[tid]; bb[tid] = b2[tid]; lp[tid] = 0.f; }
    if (blockIdx.x == 0 && tid == 0) hws3[n] = 0.f;   // zero dummy hws3
    __syncthreads();
    int nl = tid >> 2, sub = tid & 3;
    int iA = blockIdx.x * 128 + nl;
    int iB = iA + 64;
    bool actA = (iA < n), actB = (iB < n);
    float diA = actA ? dinv[iA] : 0.f;
    float diB = actB ? dinv[iB] : 0.f;
    int AA = actA ? offs[iA] : 0;
    int AB = actB ? offs[iB] : 0;
    int plA = actA ? degi[iA] : 0;
    int plB = actB ? degi[iB] : 0;
    float4 z4 = make_float4(0.f, 0.f, 0.f, 0.f);
    float4 sA = actA ? load_h4(hwsB, iA, sub) : z4;
    float4 sB = actB ? load_h4(hwsB, iB, sub) : z4;
    float4 accA = make_float4(2.f * sA.x, 2.f * sA.y, 2.f * sA.z, 2.f * sA.w);
    float4 accB = make_float4(2.f * sB.x, 2.f * sB.y, 2.f * sB.z, 2.f * sB.w);
    float4 a1A = z4, a1B = z4;
    int plM = max(plA, plB);
    for (int j = 0; j < plM; j += 8) {
        int ja = min(j, max(plA - 8, 0));
        int jb = min(j, max(plB - 8, 0));
        int4 sa0 = *reinterpret_cast<const int4*>(srcs + AA + ja);
        int4 sa1 = *reinterpret_cast<const int4*>(srcs + AA + ja + 4);
        int4 sb0 = *reinterpret_cast<const int4*>(srcs + AB + jb);
        int4 sb1 = *reinterpret_cast<const int4*>(srcs + AB + jb + 4);
        if (j >= plA) { sa0 = make_int4(n, n, n, n); sa1 = sa0; }
        if (j >= plB) { sb0 = make_int4(n, n, n, n); sb1 = sb0; }
        float4 qa0 = load_h4(hwsB, sa0.x, sub);
        float4 qa1 = load_h4(hwsB, sa0.y, sub);
        float4 qa2 = load_h4(hwsB, sa0.z, sub);
        float4 qa3 = load_h4(hwsB, sa0.w, sub);
        float4 qa4 = load_h4(hwsB, sa1.x, sub);
        float4 qa5 = load_h4(hwsB, sa1.y, sub);
        float4 qa6 = load_h4(hwsB, sa1.z, sub);
        float4 qa7 = load_h4(hwsB, sa1.w, sub);
        float4 qb0 = load_h4(hwsB, sb0.x, sub);
        float4 qb1 = load_h4(hwsB, sb0.y, sub);
        float4 qb2 = load_h4(hwsB, sb0.z, sub);
        float4 qb3 = load_h4(hwsB, sb0.w, sub);
        float4 qb4 = load_h4(hwsB, sb1.x, sub);
        float4 qb5 = load_h4(hwsB, sb1.y, sub);
        float4 qb6 = load_h4(hwsB, sb1.z, sub);
        float4 qb7 = load_h4(hwsB, sb1.w, sub);
        accA.x += qa0.x + qa2.x + qa4.x + qa6.x;
        accA.y += qa0.y + qa2.y + qa4.y + qa6.y;
        accA.z += qa0.z + qa2.z + qa4.z + qa6.z;
        accA.w += qa0.w + qa2.w + qa4.w + qa6.w;
        a1A.x += qa1.x + qa3.x + qa5.x + qa7.x;
        a1A.y += qa1.y + qa3.y + qa5.y + qa7.y;
        a1A.z += qa1.z + qa3.z + qa5.z + qa7.z;
        a1A.w += qa1.w + qa3.w + qa5.w + qa7.w;
        accB.x += qb0.x + qb2.x + qb4.x + qb6.x;
        accB.y += qb0.y + qb2.y + qb4.y + qb6.y;
        accB.z += qb0.z + qb2.z + qb4.z + qb6.z;
        accB.w += qb0.w + qb2.w + qb4.w + qb6.w;
        a1B.x += qb1.x + qb3.x + qb5.x + qb7.x;
        a1B.y += qb1.y + qb3.y + qb5.y + qb7.y;
        a1B.z += qb1.z + qb3.z + qb5.z + qb7.z;
        a1B.w += qb1.w + qb3.w + qb5.w + qb7.w;
    }
    accA.x += a1A.x; accA.y += a1A.y; accA.z += a1A.z; accA.w += a1A.w;
    accB.x += a1B.x; accB.y += a1B.y; accB.z += a1B.z; accB.w += a1B.w;
    float4 hA = z4, hB = z4;
    if (actA) {
        hA.x = fmaxf(diA * accA.x + bb[sub * 4 + 0], 0.f);
        hA.y = fmaxf(diA * accA.y + bb[sub * 4 + 1], 0.f);
        hA.z = fmaxf(diA * accA.z + bb[sub * 4 + 2], 0.f);
        hA.w = fmaxf(diA * accA.w + bb[sub * 4 + 3], 0.f);
    }
    if (actB) {
        hB.x = fmaxf(diB * accB.x + bb[sub * 4 + 0], 0.f);
        hB.y = fmaxf(diB * accB.y + bb[sub * 4 + 1], 0.f);
        hB.z = fmaxf(diB * accB.z + bb[sub * 4 + 2], 0.f);
        hB.w = fmaxf(diB * accB.w + bb[sub * 4 + 3], 0.f);
    }
    // layer-3 transform for both nodes (quad reduce)
    float pA = hA.x * w3[sub * 4 + 0] + hA.y * w3[sub * 4 + 1]
             + hA.z * w3[sub * 4 + 2] + hA.w * w3[sub * 4 + 3];
    float pB = hB.x * w3[sub * 4 + 0] + hB.y * w3[sub * 4 + 1]
             + hB.z * w3[sub * 4 + 2] + hB.w * w3[sub * 4 + 3];
    pA += __shfl_xor(pA, 1); pA += __shfl_xor(pA, 2);
    pB += __shfl_xor(pB, 1); pB += __shfl_xor(pB, 2);
    if (sub == 0) {
        if (actA) hws3[iA] = diA * pA;
        if (actB) hws3[iB] = diB * pB;
    }
    // pool: hA + hB (zeros for inactive), reduce over the wave's 16 teams
    float4 hp = make_float4(hA.x + hB.x, hA.y + hB.y, hA.z + hB.z, hA.w + hB.w);
#pragma unroll
    for (int m = 4; m < 64; m <<= 1) {
        hp.x += __shfl_xor(hp.x, m);
        hp.y += __shfl_xor(hp.y, m);
        hp.z += __shfl_xor(hp.z, m);
        hp.w += __shfl_xor(hp.w, m);
    }
    if ((tid & 63) < 4) {
        atomicAdd(&lp[sub * 4 + 0], hp.x);
        atomicAdd(&lp[sub * 4 + 1], hp.y);
        atomicAdd(&lp[sub * 4 + 2], hp.z);
        atomicAdd(&lp[sub * 4 + 3], hp.w);
    }
    __syncthreads();
    if (tid < 16) atomicAdd(&pool[tid], lp[tid]);
}

// layer-3: DUAL-NODE scalar aggregation -> logits; per-block (max, sum-exp)
__global__ void __launch_bounds__(BLK) k_agg3(const float* __restrict__ hws3,
                                              const int* __restrict__ offs,
                                              const int* __restrict__ degi,
                                              const int* __restrict__ srcs,
                                              const float* __restrict__ dinv,
                                              const float* __restrict__ b3,
                                              const int* __restrict__ choices,
                                              float* __restrict__ cbuf,
                                              float* __restrict__ bmax,
                                              float* __restrict__ bsum, int n) {
    __shared__ float red[BLK];
    int tid = threadIdx.x;
    int nl = tid >> 2, sub = tid & 3;
    int iA = blockIdx.x * 128 + nl;
    int iB = iA + 64;
    bool actA = (iA < n), actB = (iB < n);
    int AA = actA ? offs[iA] : 0;
    int AB = actB ? offs[iB] : 0;
    int plA = actA ? degi[iA] : 0;
    int plB = actB ? degi[iB] : 0;
    float sA0 = 0.f, sA1 = 0.f, sB0 = 0.f, sB1 = 0.f;
    int plM = max(plA, plB);
    for (int j = 4 * sub; j < plM; j += 16) {
        int ja = min(j, max(plA - 4, 0));
        int jb = min(j, max(plB - 4, 0));
        int4 sa = *reinterpret_cast<const int4*>(srcs + AA + ja);
        int4 sb = *reinterpret_cast<const int4*>(srcs + AB + jb);
        if (j >= plA) sa = make_int4(n, n, n, n);
        if (j >= plB) sb = make_int4(n, n, n, n);
        sA0 += hws3[sa.x] + hws3[sa.z];
        sA1 += hws3[sa.y] + hws3[sa.w];
        sB0 += hws3[sb.x] + hws3[sb.z];
        sB1 += hws3[sb.y] + hws3[sb.w];
    }
    float sA = sA0 + sA1, sB = sB0 + sB1;
    sA += __shfl_xor(sA, 1); sA += __shfl_xor(sA, 2);
    sB += __shfl_xor(sB, 1); sB += __shfl_xor(sB, 2);
    float lA = -INFINITY, lB = -INFINITY;
    if (sub == 0) {
        if (actA) {
            float c = dinv[iA] * (sA + 2.f * hws3[iA]) + b3[0];
            cbuf[iA] = c;
            if (choices[iA] != 0) lA = c;
        }
        if (actB) {
            float c = dinv[iB] * (sB + 2.f * hws3[iB]) + b3[0];
            cbuf[iB] = c;
            if (choices[iB] != 0) lB = c;
        }
    }
    red[tid] = fmaxf(lA, lB);
    __syncthreads();
    for (int d = BLK / 2; d > 0; d >>= 1) {
        if (tid < d) red[tid] = fmaxf(red[tid], red[tid + d]);
        __syncthreads();
    }
    float bm = red[0];
    __syncthreads();
    float es = 0.f;
    if (lA > -INFINITY) es += expf(lA - bm);
    if (lB > -INFINITY) es += expf(lB - bm);
    red[tid] = es;
    __syncthreads();
    for (int d = BLK / 2; d > 0; d >>= 1) {
        if (tid < d) red[tid] += red[tid + d];
        __syncthreads();
    }
    if (tid == 0) { bmax[blockIdx.x] = bm; bsum[blockIdx.x] = red[0]; }
}

// final: every block redundantly combines per-block (max,sum) -> (M,S),
// then writes probabilities; block 0 writes the value head.
__global__ void __launch_bounds__(BLK) k_final(const float* __restrict__ cbuf,
                                               const int* __restrict__ choices,
                                               const float* __restrict__ bmax,
                                               const float* __restrict__ bsum,
                                               const float* __restrict__ pool,
                                               const float* __restrict__ fcw,
                                               const float* __restrict__ fcb,
                                               float* __restrict__ out,
                                               int nblk, int n) {
    __shared__ float red[BLK];
    __shared__ float MS[2];
    int tid = threadIdx.x;
    float m = -INFINITY;
    for (int i = tid; i < nblk; i += BLK) m = fmaxf(m, bmax[i]);
    red[tid] = m;
    __syncthreads();
    for (int d = BLK / 2; d > 0; d >>= 1) {
        if (tid < d) red[tid] = fmaxf(red[tid], red[tid + d]);
        __syncthreads();
    }
    float M = red[0];
    __syncthreads();
    float s = 0.f;
    for (int i = tid; i < nblk; i += BLK) {
        float bm = bmax[i];
        if (bm > -INFINITY) s += bsum[i] * expf(bm - M);
    }
    red[tid] = s;
    __syncthreads();
    for (int d = BLK / 2; d > 0; d >>= 1) {
        if (tid < d) red[tid] += red[tid + d];
        __syncthreads();
    }
    if (tid == 0) { MS[0] = M; MS[1] = red[0]; }
    __syncthreads();
    float Mv = MS[0], Sv = MS[1];
    int i = blockIdx.x * BLK + tid;
    if (i < n) {
        float p = 0.0f;
        if (choices[i] != 0) p = expf(cbuf[i] - Mv) / Sv;
        out[i] = p;
    }
    if (blockIdx.x == 0 && tid == 0) {
        float invn = 1.0f / (float)n;
        float v = 0.0f;
#pragma unroll
        for (int f = 0; f < 16; f++) v += (pool[f] * invn) * fcw[f];
        out[n] = v + fcb[0];
    }
}

extern "C" void kernel_launch(void* const* d_in, const int* in_sizes, int n_in,
                              void* d_out, int out_size, void* d_ws, size_t ws_size,
                              hipStream_t stream) {
    const float* x       = (const float*)d_in[0];
    const int*   ei      = (const int*)d_in[1];
    const int*   choices = (const int*)d_in[2];
    const float* W1 = (const float*)d_in[3];
    const float* b1 = (const float*)d_in[4];
    const float* W2 = (const float*)d_in[5];
    const float* b2 = (const float*)d_in[6];
    const float* W3 = (const float*)d_in[7];
    const float* b3 = (const float*)d_in[8];
    const float* fcw = (const float*)d_in[9];
    const float* fcb = (const float*)d_in[10];
    float* out = (float*)d_out;

    int n = in_sizes[0] / 3;
    int E = in_sizes[1] / 2;
    const int* row = ei;
    const int* col = ei + E;

    int nblkN = (n + BLK - 1) / BLK;           // 391
    int nblk64 = (n + 63) / 64;                // 1563  (k_agg1)
    int nblk128 = (n + 127) / 128;             // 782   (dual-node kernels)
    int nbuck = (n + (1 << BSH) - 1) >> BSH;   // 391 buckets of 256 nodes
    int nblkBin = (E + EB - 1) / EB;           // 391 binning blocks

    // workspace layout (16B aligned slices); ws_size is ~268 MB, plenty
    char* ws = (char*)d_ws;
    size_t o = 0;
    auto alloc = [&](size_t bytes) { char* p = ws + o; o += (bytes + 15) & ~(size_t)15; return p; };
    int*   degi   = (int*)  alloc((size_t)n * 4);
    int*   offs   = (int*)  alloc((size_t)n * 4);
    float* dinv   = (float*)alloc((size_t)n * 4);
    float* hws3   = (float*)alloc((size_t)(n + 1) * 4);  // +1: dummy node
    float* cbuf   = (float*)alloc((size_t)n * 4);
    float* bmax   = (float*)alloc(8192);       // >= nblk128 floats
    float* bsum   = (float*)alloc(8192);
    int*   gcur   = (int*)  alloc(NB * 4);
    float* scal   = (float*)alloc(256);   // [0]=S(unused), [1..16]=pool, [17]=m
    float* pool   = scal + 1;
    __half* xs    = (__half*)alloc((size_t)(n + 1) * 4 * 2);  // half4/node +dummy
    size_t hw_bytes = (size_t)(n + 1) * 16 * 2;          // hwsB (fp16) + dummy
    size_t pk_bytes = (size_t)NB * CAP * 4;              // packed (capacity layout)
    char*  blob   = alloc(hw_bytes > pk_bytes ? hw_bytes : pk_bytes);
    int*    packed = (int*)blob;          // build phase only; dead before k_agg1
    __half* hwsB   = (__half*)blob;
    int*   srcs   = (int*)  alloc((size_t)NB * SCAP * 4);    // capacity layout
    (void)ws_size;  // ~65 MB used

    // ---- build (2 passes over edges; no per-edge global atomics) ----
    k_init<<<1, NB, 0, stream>>>(gcur, scal);
    k_bin<<<nblkBin, BINTH, 0, stream>>>(row, col, gcur, packed, E);
    k_place<<<nbuck, BLK, 0, stream>>>(packed, gcur, x, degi, offs, dinv, xs, srcs, n);

    // ---- GCN layers ----
    k_agg1<<<nblk64, BLK, 0, stream>>>(xs, offs, degi, srcs, dinv, b1, W1, W2, hwsB, n);
    k_agg2<<<nblk128, BLK, 0, stream>>>(hwsB, offs, degi, srcs, dinv, b2, W3, hws3, pool, n);
    k_agg3<<<nblk128, BLK, 0, stream>>>(hws3, offs, degi, srcs, dinv, b3, choices, cbuf, bmax, bsum, n);

    // ---- softmax combine fused into final ----
    k_final<<<nblkN, BLK, 0, stream>>>(cbuf, choices, bmax, bsum, pool, fcw, fcb, out, nblk128, n);
}

// Round 13
// 222.982 us; speedup vs baseline: 1.1783x; 1.0126x over previous
//
#include <hip/hip_runtime.h>
#include <hip/hip_fp16.h>
#include <math.h>

#define BLK 256

// ---------------------------------------------------------------------------
// GCNPolicyNetwork: 3-layer improved-GCN + masked softmax + mean-pool value.
// Round 13: apply the twice-verified MLP lever (R9 unroll, R12 dual-node)
// everywhere: (1) k_agg1 dual-node (i, i+64 per 4-lane team, 128 nodes/blk);
// (2) k_bin BINTH 512->1024 (same 56KB LDS -> 2 blocks/CU, but 32 waves/CU
// instead of 16 to hide the col/row stream); (3) k_agg3 8-index chunks
// (stride 32, 2x int4 loads in flight). Linear node order kept (R10 lesson);
// x8-padded dummy-node srcs (R12) make all gathers branchless.
// ---------------------------------------------------------------------------

#define BSH 8                    // 256 nodes per bucket
#define NB 512                   // bucket-array size (nbuck=391 <= 512)
#define CAP 10240                // packed[] capacity per bucket (mean ~8184)
#define SCAP 12288               // srcs[] capacity per bucket (CAP + 8*256 pad)
#define EB 8192                  // edges per binning block
#define BINTH 1024               // k_bin block size (R13: was 512)

// ---- fp16 payload helpers ----
__device__ inline float4 load_h4(const __half* base, int node, int sub) {
    const uint2* p = reinterpret_cast<const uint2*>(base + ((size_t)node << 4)) + sub;
    uint2 u = *p;
    union { unsigned u; __half2 h; } a, b;
    a.u = u.x; b.u = u.y;
    float2 fa = __half22float2(a.h), fb = __half22float2(b.h);
    return make_float4(fa.x, fa.y, fb.x, fb.y);
}

__device__ inline void store_h4(__half* base, int node, int sub, float4 v) {
    union { unsigned u; __half2 h; } a, b;
    a.h = __floats2half2_rn(v.x, v.y);
    b.h = __floats2half2_rn(v.z, v.w);
    uint2 u; u.x = a.u; u.y = b.u;
    *(reinterpret_cast<uint2*>(base + ((size_t)node << 4)) + sub) = u;
}

// xs payload: half4 (dinv*x0, dinv*x1, dinv*x2, 0) = 8 B per node
__device__ inline float3 load_xs(const __half* xs, int node) {
    uint2 u = *reinterpret_cast<const uint2*>(xs + ((size_t)node << 2));
    union { unsigned u; __half2 h; } a, b;
    a.u = u.x; b.u = u.y;
    float2 fa = __half22float2(a.h), fb = __half22float2(b.h);
    return make_float3(fa.x, fa.y, fb.x);
}

// zero gcur[NB] + scal[18]
__global__ void k_init(int* __restrict__ gcur, float* __restrict__ scal) {
    int t = threadIdx.x;
    gcur[t] = 0;
    if (t < 18) scal[t] = 0.f;
}

// LDS multisplit of edges into 256-node buckets; reserve directly in the
// fixed-capacity packed[] layout (bucket b owns [b*CAP, b*CAP+cnt)).
__global__ void __launch_bounds__(BINTH) k_bin(const int* __restrict__ row,
                                               const int* __restrict__ col,
                                               int* __restrict__ gcur,
                                               int* __restrict__ packed, int E) {
    __shared__ int stage[EB];
    __shared__ unsigned short sbuk[EB];
    __shared__ int hist[NB];
    __shared__ int lscan[NB];
    __shared__ int cur[NB];
    __shared__ int gbase[NB];
    int tid = threadIdx.x;
    int base = blockIdx.x * EB;
    int cnt = min(EB, E - base);

    if (tid < NB) hist[tid] = 0;
    __syncthreads();
    for (int j = tid; j < cnt; j += BINTH) {
        int c = __builtin_nontemporal_load(col + base + j);
        atomicAdd(&hist[c >> BSH], 1);
    }
    __syncthreads();
    if (tid < NB) lscan[tid] = hist[tid];
    __syncthreads();
    for (int d = 1; d < NB; d <<= 1) {
        int t = (tid < NB && tid >= d) ? lscan[tid - d] : 0;
        __syncthreads();
        if (tid < NB && tid >= d) lscan[tid] += t;
        __syncthreads();
    }
    if (tid < NB) {
        int ex = lscan[tid] - hist[tid];
        lscan[tid] = ex;
        cur[tid] = ex;
    }
    __syncthreads();
    for (int j = tid; j < cnt; j += BINTH) {
        int c = __builtin_nontemporal_load(col + base + j);
        int r = __builtin_nontemporal_load(row + base + j);
        int b = c >> BSH;
        int p = atomicAdd(&cur[b], 1);
        stage[p] = (r << BSH) | (c & ((1 << BSH) - 1));
        sbuk[p] = (unsigned short)b;
    }
    __syncthreads();
    if (tid < NB && hist[tid] > 0)
        gbase[tid] = tid * CAP + atomicAdd(&gcur[tid], hist[tid]);
    __syncthreads();
    for (int j = tid; j < cnt; j += BINTH) {
        int b = sbuk[j];
        int pos = gbase[b] + (j - lscan[b]);
        packed[pos] = stage[j];
    }
}

// per-bucket: degree hist + scan of PADDED(x8) lengths -> degi/offs/dinv/xs,
// dummy-pad fill, then fine placement into srcs (capacity layout, x8-aligned).
__global__ void __launch_bounds__(BLK) k_place(const int* __restrict__ packed,
                                               const int* __restrict__ bcnt,
                                               const float* __restrict__ x,
                                               int* __restrict__ degi,
                                               int* __restrict__ offs,
                                               float* __restrict__ dinv,
                                               __half* __restrict__ xs,
                                               int* __restrict__ srcs, int n) {
    __shared__ int cnt[256];
    __shared__ int lcur[256];
    __shared__ int ssum[256];
    int tid = threadIdx.x;
    int b = blockIdx.x;
    int nb0 = b << BSH;
    cnt[tid] = 0;
    __syncthreads();
    int ecnt = bcnt[b];
    const int* pk = packed + (size_t)b * CAP;
    for (int j = tid; j < ecnt; j += BLK)
        atomicAdd(&cnt[pk[j] & 255], 1);
    __syncthreads();
    int c = cnt[tid];
    int pl = (c + 7) & ~7;                 // padded length (x8)
    ssum[tid] = pl;
    __syncthreads();
    for (int d = 1; d < 256; d <<= 1) {
        int t = (tid >= d) ? ssum[tid - d] : 0;
        __syncthreads();
        if (tid >= d) ssum[tid] += t;
        __syncthreads();
    }
    int A = b * SCAP + (ssum[tid] - pl);   // absolute aligned base for node
    lcur[tid] = A;
    int valid = min(n - nb0, 256);
    int i = nb0 + tid;
    if (tid < valid) {
        degi[i] = pl;
        offs[i] = A;
        float di = rsqrtf((float)c + 2.0f);
        dinv[i] = di;
        float x0 = x[i * 3 + 0], x1 = x[i * 3 + 1], x2 = x[i * 3 + 2];
        union { unsigned u; __half2 h; } a2, b2;
        a2.h = __floats2half2_rn(di * x0, di * x1);
        b2.h = __floats2half2_rn(di * x2, 0.f);
        uint2 u; u.x = a2.u; u.y = b2.u;
        *reinterpret_cast<uint2*>(xs + ((size_t)i << 2)) = u;
        for (int k = c; k < pl; k++) srcs[A + k] = n;   // dummy pads
    }
    if (b == 0 && tid == 0) {              // zero the dummy xs payload
        uint2 z; z.x = 0u; z.y = 0u;
        *reinterpret_cast<uint2*>(xs + ((size_t)n << 2)) = z;
    }
    __syncthreads();
    for (int j = tid; j < ecnt; j += BLK) {
        int v = pk[j];
        int li = v & 255;
        int slot = atomicAdd(&lcur[li], 1);
        srcs[slot] = v >> BSH;
    }
}

// layer-1: DUAL-NODE rank-3 aggregation of xs, then @W1+relu, @W2 -> hwsB.
// Team of 4 lanes walks nodes iA and iB=iA+64 together (128 nodes/block).
__global__ void __launch_bounds__(BLK) k_agg1(const __half* __restrict__ xs,
                                              const int* __restrict__ offs,
                                              const int* __restrict__ degi,
                                              const int* __restrict__ srcs,
                                              const float* __restrict__ dinv,
                                              const float* __restrict__ b1,
                                              const float* __restrict__ W1,
                                              const float* __restrict__ W2,
                                              __half* __restrict__ hwsB, int n) {
    __shared__ float w1[48];
    __shared__ float w2[256];
    __shared__ float bb[16];
    __shared__ float hbuf[128][17];
    int tid = threadIdx.x;
    w2[tid] = W2[tid];
    if (tid < 48) w1[tid] = W1[tid];
    if (tid < 16) bb[tid] = b1[tid];
    if (blockIdx.x == 0 && tid < 8)        // zero the dummy hwsB payload (32 B)
        reinterpret_cast<unsigned*>(hwsB + ((size_t)n << 4))[tid] = 0u;
    __syncthreads();
    int nl = tid >> 2, sub = tid & 3;
    int iA = blockIdx.x * 128 + nl;
    int iB = iA + 64;
    bool actA = (iA < n), actB = (iB < n);
    int AA = actA ? offs[iA] : 0;
    int AB = actB ? offs[iB] : 0;
    int plA = actA ? degi[iA] : 0;
    int plB = actB ? degi[iB] : 0;
    float axA = 0.f, ayA = 0.f, azA = 0.f;
    float axB = 0.f, ayB = 0.f, azB = 0.f;
    int plM = max(plA, plB);
    for (int j = 4 * sub; j < plM; j += 16) {
        int ja = min(j, max(plA - 4, 0));
        int jb = min(j, max(plB - 4, 0));
        int4 sa = *reinterpret_cast<const int4*>(srcs + AA + ja);
        int4 sb = *reinterpret_cast<const int4*>(srcs + AB + jb);
        if (j >= plA) sa = make_int4(n, n, n, n);
        if (j >= plB) sb = make_int4(n, n, n, n);
        float3 qa0 = load_xs(xs, sa.x);
        float3 qa1 = load_xs(xs, sa.y);
        float3 qa2 = load_xs(xs, sa.z);
        float3 qa3 = load_xs(xs, sa.w);
        float3 qb0 = load_xs(xs, sb.x);
        float3 qb1 = load_xs(xs, sb.y);
        float3 qb2 = load_xs(xs, sb.z);
        float3 qb3 = load_xs(xs, sb.w);
        axA += qa0.x + qa1.x + qa2.x + qa3.x;
        ayA += qa0.y + qa1.y + qa2.y + qa3.y;
        azA += qa0.z + qa1.z + qa2.z + qa3.z;
        axB += qb0.x + qb1.x + qb2.x + qb3.x;
        ayB += qb0.y + qb1.y + qb2.y + qb3.y;
        azB += qb0.z + qb1.z + qb2.z + qb3.z;
    }
    axA += __shfl_xor(axA, 1); ayA += __shfl_xor(ayA, 1); azA += __shfl_xor(azA, 1);
    axA += __shfl_xor(axA, 2); ayA += __shfl_xor(ayA, 2); azA += __shfl_xor(azA, 2);
    axB += __shfl_xor(axB, 1); ayB += __shfl_xor(ayB, 1); azB += __shfl_xor(azB, 1);
    axB += __shfl_xor(axB, 2); ayB += __shfl_xor(ayB, 2); azB += __shfl_xor(azB, 2);
    float diA = 0.f, diB = 0.f;
    if (actA) {
        diA = dinv[iA];
        float3 s = load_xs(xs, iA);
        float ax = axA + 2.f * s.x, ay = ayA + 2.f * s.y, az = azA + 2.f * s.z;
#pragma unroll
        for (int k = 0; k < 4; k++) {
            int f = sub * 4 + k;
            float hv = diA * (ax * w1[f] + ay * w1[16 + f] + az * w1[32 + f]) + bb[f];
            hbuf[nl][f] = fmaxf(hv, 0.f);
        }
    }
    if (actB) {
        diB = dinv[iB];
        float3 s = load_xs(xs, iB);
        float ax = axB + 2.f * s.x, ay = ayB + 2.f * s.y, az = azB + 2.f * s.z;
#pragma unroll
        for (int k = 0; k < 4; k++) {
            int f = sub * 4 + k;
            float hv = diB * (ax * w1[f] + ay * w1[16 + f] + az * w1[32 + f]) + bb[f];
            hbuf[64 + nl][f] = fmaxf(hv, 0.f);
        }
    }
    __syncthreads();
    if (actA) {
        const float* hn = hbuf[nl];
        float s0 = 0.f, s1 = 0.f, s2 = 0.f, s3 = 0.f;
#pragma unroll
        for (int f = 0; f < 16; f++) {
            float hv = hn[f];
            const float4 wq = *(const float4*)&w2[f * 16 + sub * 4];
            s0 += hv * wq.x; s1 += hv * wq.y; s2 += hv * wq.z; s3 += hv * wq.w;
        }
        store_h4(hwsB, iA, sub, make_float4(diA * s0, diA * s1, diA * s2, diA * s3));
    }
    if (actB) {
        const float* hn = hbuf[64 + nl];
        float s0 = 0.f, s1 = 0.f, s2 = 0.f, s3 = 0.f;
#pragma unroll
        for (int f = 0; f < 16; f++) {
            float hv = hn[f];
            const float4 wq = *(const float4*)&w2[f * 16 + sub * 4];
            s0 += hv * wq.x; s1 += hv * wq.y; s2 += hv * wq.z; s3 += hv * wq.w;
        }
        store_h4(hwsB, iB, sub, make_float4(diB * s0, diB * s1, diB * s2, diB * s3));
    }
}

// layer-2: DUAL-NODE interleaved gather + relu + pool + layer-3 transform.
__global__ void __launch_bounds__(BLK) k_agg2(const __half* __restrict__ hwsB,
                                              const int* __restrict__ offs,
                                              const int* __restrict__ degi,
                                              const int* __restrict__ srcs,
                                              const float* __restrict__ dinv,
                                              const float* __restrict__ b2,
                                              const float* __restrict__ W3,
                                              float* __restrict__ hws3,
                                              float* __restrict__ pool, int n) {
    __shared__ float w3[16];
    __shared__ float bb[16];
    __shared__ float lp[16];
    int tid = threadIdx.x;
    if (tid < 16) { w3[tid] = W3[tid]; bb[tid] = b2[tid]; lp[tid] = 0.f; }
    if (blockIdx.x == 0 && tid == 0) hws3[n] = 0.f;   // zero dummy hws3
    __syncthreads();
    int nl = tid >> 2, sub = tid & 3;
    int iA = blockIdx.x * 128 + nl;
    int iB = iA + 64;
    bool actA = (iA < n), actB = (iB < n);
    float diA = actA ? dinv[iA] : 0.f;
    float diB = actB ? dinv[iB] : 0.f;
    int AA = actA ? offs[iA] : 0;
    int AB = actB ? offs[iB] : 0;
    int plA = actA ? degi[iA] : 0;
    int plB = actB ? degi[iB] : 0;
    float4 z4 = make_float4(0.f, 0.f, 0.f, 0.f);
    float4 sA = actA ? load_h4(hwsB, iA, sub) : z4;
    float4 sB = actB ? load_h4(hwsB, iB, sub) : z4;
    float4 accA = make_float4(2.f * sA.x, 2.f * sA.y, 2.f * sA.z, 2.f * sA.w);
    float4 accB = make_float4(2.f * sB.x, 2.f * sB.y, 2.f * sB.z, 2.f * sB.w);
    float4 a1A = z4, a1B = z4;
    int plM = max(plA, plB);
    for (int j = 0; j < plM; j += 8) {
        int ja = min(j, max(plA - 8, 0));
        int jb = min(j, max(plB - 8, 0));
        int4 sa0 = *reinterpret_cast<const int4*>(srcs + AA + ja);
        int4 sa1 = *reinterpret_cast<const int4*>(srcs + AA + ja + 4);
        int4 sb0 = *reinterpret_cast<const int4*>(srcs + AB + jb);
        int4 sb1 = *reinterpret_cast<const int4*>(srcs + AB + jb + 4);
        if (j >= plA) { sa0 = make_int4(n, n, n, n); sa1 = sa0; }
        if (j >= plB) { sb0 = make_int4(n, n, n, n); sb1 = sb0; }
        float4 qa0 = load_h4(hwsB, sa0.x, sub);
        float4 qa1 = load_h4(hwsB, sa0.y, sub);
        float4 qa2 = load_h4(hwsB, sa0.z, sub);
        float4 qa3 = load_h4(hwsB, sa0.w, sub);
        float4 qa4 = load_h4(hwsB, sa1.x, sub);
        float4 qa5 = load_h4(hwsB, sa1.y, sub);
        float4 qa6 = load_h4(hwsB, sa1.z, sub);
        float4 qa7 = load_h4(hwsB, sa1.w, sub);
        float4 qb0 = load_h4(hwsB, sb0.x, sub);
        float4 qb1 = load_h4(hwsB, sb0.y, sub);
        float4 qb2 = load_h4(hwsB, sb0.z, sub);
        float4 qb3 = load_h4(hwsB, sb0.w, sub);
        float4 qb4 = load_h4(hwsB, sb1.x, sub);
        float4 qb5 = load_h4(hwsB, sb1.y, sub);
        float4 qb6 = load_h4(hwsB, sb1.z, sub);
        float4 qb7 = load_h4(hwsB, sb1.w, sub);
        accA.x += qa0.x + qa2.x + qa4.x + qa6.x;
        accA.y += qa0.y + qa2.y + qa4.y + qa6.y;
        accA.z += qa0.z + qa2.z + qa4.z + qa6.z;
        accA.w += qa0.w + qa2.w + qa4.w + qa6.w;
        a1A.x += qa1.x + qa3.x + qa5.x + qa7.x;
        a1A.y += qa1.y + qa3.y + qa5.y + qa7.y;
        a1A.z += qa1.z + qa3.z + qa5.z + qa7.z;
        a1A.w += qa1.w + qa3.w + qa5.w + qa7.w;
        accB.x += qb0.x + qb2.x + qb4.x + qb6.x;
        accB.y += qb0.y + qb2.y + qb4.y + qb6.y;
        accB.z += qb0.z + qb2.z + qb4.z + qb6.z;
        accB.w += qb0.w + qb2.w + qb4.w + qb6.w;
        a1B.x += qb1.x + qb3.x + qb5.x + qb7.x;
        a1B.y += qb1.y + qb3.y + qb5.y + qb7.y;
        a1B.z += qb1.z + qb3.z + qb5.z + qb7.z;
        a1B.w += qb1.w + qb3.w + qb5.w + qb7.w;
    }
    accA.x += a1A.x; accA.y += a1A.y; accA.z += a1A.z; accA.w += a1A.w;
    accB.x += a1B.x; accB.y += a1B.y; accB.z += a1B.z; accB.w += a1B.w;
    float4 hA = z4, hB = z4;
    if (actA) {
        hA.x = fmaxf(diA * accA.x + bb[sub * 4 + 0], 0.f);
        hA.y = fmaxf(diA * accA.y + bb[sub * 4 + 1], 0.f);
        hA.z = fmaxf(diA * accA.z + bb[sub * 4 + 2], 0.f);
        hA.w = fmaxf(diA * accA.w + bb[sub * 4 + 3], 0.f);
    }
    if (actB) {
        hB.x = fmaxf(diB * accB.x + bb[sub * 4 + 0], 0.f);
        hB.y = fmaxf(diB * accB.y + bb[sub * 4 + 1], 0.f);
        hB.z = fmaxf(diB * accB.z + bb[sub * 4 + 2], 0.f);
        hB.w = fmaxf(diB * accB.w + bb[sub * 4 + 3], 0.f);
    }
    float pA = hA.x * w3[sub * 4 + 0] + hA.y * w3[sub * 4 + 1]
             + hA.z * w3[sub * 4 + 2] + hA.w * w3[sub * 4 + 3];
    float pB = hB.x * w3[sub * 4 + 0] + hB.y * w3[sub * 4 + 1]
             + hB.z * w3[sub * 4 + 2] + hB.w * w3[sub * 4 + 3];
    pA += __shfl_xor(pA, 1); pA += __shfl_xor(pA, 2);
    pB += __shfl_xor(pB, 1); pB += __shfl_xor(pB, 2);
    if (sub == 0) {
        if (actA) hws3[iA] = diA * pA;
        if (actB) hws3[iB] = diB * pB;
    }
    float4 hp = make_float4(hA.x + hB.x, hA.y + hB.y, hA.z + hB.z, hA.w + hB.w);
#pragma unroll
    for (int m = 4; m < 64; m <<= 1) {
        hp.x += __shfl_xor(hp.x, m);
        hp.y += __shfl_xor(hp.y, m);
        hp.z += __shfl_xor(hp.z, m);
        hp.w += __shfl_xor(hp.w, m);
    }
    if ((tid & 63) < 4) {
        atomicAdd(&lp[sub * 4 + 0], hp.x);
        atomicAdd(&lp[sub * 4 + 1], hp.y);
        atomicAdd(&lp[sub * 4 + 2], hp.z);
        atomicAdd(&lp[sub * 4 + 3], hp.w);
    }
    __syncthreads();
    if (tid < 16) atomicAdd(&pool[tid], lp[tid]);
}

// layer-3: DUAL-NODE scalar aggregation (8-index chunks per lane, stride 32)
// -> logits; per-block (max, sum-exp) for the fused softmax.
__global__ void __launch_bounds__(BLK) k_agg3(const float* __restrict__ hws3,
                                              const int* __restrict__ offs,
                                              const int* __restrict__ degi,
                                              const int* __restrict__ srcs,
                                              const float* __restrict__ dinv,
                                              const float* __restrict__ b3,
                                              const int* __restrict__ choices,
                                              float* __restrict__ cbuf,
                                              float* __restrict__ bmax,
                                              float* __restrict__ bsum, int n) {
    __shared__ float red[BLK];
    int tid = threadIdx.x;
    int nl = tid >> 2, sub = tid & 3;
    int iA = blockIdx.x * 128 + nl;
    int iB = iA + 64;
    bool actA = (iA < n), actB = (iB < n);
    int AA = actA ? offs[iA] : 0;
    int AB = actB ? offs[iB] : 0;
    int plA = actA ? degi[iA] : 0;
    int plB = actB ? degi[iB] : 0;
    float sA0 = 0.f, sA1 = 0.f, sB0 = 0.f, sB1 = 0.f;
    int plM = max(plA, plB);
    for (int j = 8 * sub; j < plM; j += 32) {
        int ja = min(j, max(plA - 8, 0));
        int jb = min(j, max(plB - 8, 0));
        int4 sa0 = *reinterpret_cast<const int4*>(srcs + AA + ja);
        int4 sa1 = *reinterpret_cast<const int4*>(srcs + AA + ja + 4);
        int4 sb0 = *reinterpret_cast<const int4*>(srcs + AB + jb);
        int4 sb1 = *reinterpret_cast<const int4*>(srcs + AB + jb + 4);
        if (j >= plA) { sa0 = make_int4(n, n, n, n); sa1 = sa0; }
        if (j >= plB) { sb0 = make_int4(n, n, n, n); sb1 = sb0; }
        sA0 += hws3[sa0.x] + hws3[sa0.z] + hws3[sa1.x] + hws3[sa1.z];
        sA1 += hws3[sa0.y] + hws3[sa0.w] + hws3[sa1.y] + hws3[sa1.w];
        sB0 += hws3[sb0.x] + hws3[sb0.z] + hws3[sb1.x] + hws3[sb1.z];
        sB1 += hws3[sb0.y] + hws3[sb0.w] + hws3[sb1.y] + hws3[sb1.w];
    }
    float sA = sA0 + sA1, sB = sB0 + sB1;
    sA += __shfl_xor(sA, 1); sA += __shfl_xor(sA, 2);
    sB += __shfl_xor(sB, 1); sB += __shfl_xor(sB, 2);
    float lA = -INFINITY, lB = -INFINITY;
    if (sub == 0) {
        if (actA) {
            float c = dinv[iA] * (sA + 2.f * hws3[iA]) + b3[0];
            cbuf[iA] = c;
            if (choices[iA] != 0) lA = c;
        }
        if (actB) {
            float c = dinv[iB] * (sB + 2.f * hws3[iB]) + b3[0];
            cbuf[iB] = c;
            if (choices[iB] != 0) lB = c;
        }
    }
    red[tid] = fmaxf(lA, lB);
    __syncthreads();
    for (int d = BLK / 2; d > 0; d >>= 1) {
        if (tid < d) red[tid] = fmaxf(red[tid], red[tid + d]);
        __syncthreads();
    }
    float bm = red[0];
    __syncthreads();
    float es = 0.f;
    if (lA > -INFINITY) es += expf(lA - bm);
    if (lB > -INFINITY) es += expf(lB - bm);
    red[tid] = es;
    __syncthreads();
    for (int d = BLK / 2; d > 0; d >>= 1) {
        if (tid < d) red[tid] += red[tid + d];
        __syncthreads();
    }
    if (tid == 0) { bmax[blockIdx.x] = bm; bsum[blockIdx.x] = red[0]; }
}

// final: every block redundantly combines per-block (max,sum) -> (M,S),
// then writes probabilities; block 0 writes the value head.
__global__ void __launch_bounds__(BLK) k_final(const float* __restrict__ cbuf,
                                               const int* __restrict__ choices,
                                               const float* __restrict__ bmax,
                                               const float* __restrict__ bsum,
                                               const float* __restrict__ pool,
                                               const float* __restrict__ fcw,
                                               const float* __restrict__ fcb,
                                               float* __restrict__ out,
                                               int nblk, int n) {
    __shared__ float red[BLK];
    __shared__ float MS[2];
    int tid = threadIdx.x;
    float m = -INFINITY;
    for (int i = tid; i < nblk; i += BLK) m = fmaxf(m, bmax[i]);
    red[tid] = m;
    __syncthreads();
    for (int d = BLK / 2; d > 0; d >>= 1) {
        if (tid < d) red[tid] = fmaxf(red[tid], red[tid + d]);
        __syncthreads();
    }
    float M = red[0];
    __syncthreads();
    float s = 0.f;
    for (int i = tid; i < nblk; i += BLK) {
        float bm = bmax[i];
        if (bm > -INFINITY) s += bsum[i] * expf(bm - M);
    }
    red[tid] = s;
    __syncthreads();
    for (int d = BLK / 2; d > 0; d >>= 1) {
        if (tid < d) red[tid] += red[tid + d];
        __syncthreads();
    }
    if (tid == 0) { MS[0] = M; MS[1] = red[0]; }
    __syncthreads();
    float Mv = MS[0], Sv = MS[1];
    int i = blockIdx.x * BLK + tid;
    if (i < n) {
        float p = 0.0f;
        if (choices[i] != 0) p = expf(cbuf[i] - Mv) / Sv;
        out[i] = p;
    }
    if (blockIdx.x == 0 && tid == 0) {
        float invn = 1.0f / (float)n;
        float v = 0.0f;
#pragma unroll
        for (int f = 0; f < 16; f++) v += (pool[f] * invn) * fcw[f];
        out[n] = v + fcb[0];
    }
}

extern "C" void kernel_launch(void* const* d_in, const int* in_sizes, int n_in,
                              void* d_out, int out_size, void* d_ws, size_t ws_size,
                              hipStream_t stream) {
    const float* x       = (const float*)d_in[0];
    const int*   ei      = (const int*)d_in[1];
    const int*   choices = (const int*)d_in[2];
    const float* W1 = (const float*)d_in[3];
    const float* b1 = (const float*)d_in[4];
    const float* W2 = (const float*)d_in[5];
    const float* b2 = (const float*)d_in[6];
    const float* W3 = (const float*)d_in[7];
    const float* b3 = (const float*)d_in[8];
    const float* fcw = (const float*)d_in[9];
    const float* fcb = (const float*)d_in[10];
    float* out = (float*)d_out;

    int n = in_sizes[0] / 3;
    int E = in_sizes[1] / 2;
    const int* row = ei;
    const int* col = ei + E;

    int nblkN = (n + BLK - 1) / BLK;           // 391
    int nblk128 = (n + 127) / 128;             // 782   (dual-node kernels)
    int nbuck = (n + (1 << BSH) - 1) >> BSH;   // 391 buckets of 256 nodes
    int nblkBin = (E + EB - 1) / EB;           // 391 binning blocks

    // workspace layout (16B aligned slices); ws_size is ~268 MB, plenty
    char* ws = (char*)d_ws;
    size_t o = 0;
    auto alloc = [&](size_t bytes) { char* p = ws + o; o += (bytes + 15) & ~(size_t)15; return p; };
    int*   degi   = (int*)  alloc((size_t)n * 4);
    int*   offs   = (int*)  alloc((size_t)n * 4);
    float* dinv   = (float*)alloc((size_t)n * 4);
    float* hws3   = (float*)alloc((size_t)(n + 1) * 4);  // +1: dummy node
    float* cbuf   = (float*)alloc((size_t)n * 4);
    float* bmax   = (float*)alloc(8192);       // >= nblk128 floats
    float* bsum   = (float*)alloc(8192);
    int*   gcur   = (int*)  alloc(NB * 4);
    float* scal   = (float*)alloc(256);   // [1..16]=pool
    float* pool   = scal + 1;
    __half* xs    = (__half*)alloc((size_t)(n + 1) * 4 * 2);  // half4/node +dummy
    size_t hw_bytes = (size_t)(n + 1) * 16 * 2;          // hwsB (fp16) + dummy
    size_t pk_bytes = (size_t)NB * CAP * 4;              // packed (capacity layout)
    char*  blob   = alloc(hw_bytes > pk_bytes ? hw_bytes : pk_bytes);
    int*    packed = (int*)blob;          // build phase only; dead before k_agg1
    __half* hwsB   = (__half*)blob;
    int*   srcs   = (int*)  alloc((size_t)NB * SCAP * 4);    // capacity layout
    (void)ws_size;  // ~65 MB used

    // ---- build (2 passes over edges; no per-edge global atomics) ----
    k_init<<<1, NB, 0, stream>>>(gcur, scal);
    k_bin<<<nblkBin, BINTH, 0, stream>>>(row, col, gcur, packed, E);
    k_place<<<nbuck, BLK, 0, stream>>>(packed, gcur, x, degi, offs, dinv, xs, srcs, n);

    // ---- GCN layers (all dual-node) ----
    k_agg1<<<nblk128, BLK, 0, stream>>>(xs, offs, degi, srcs, dinv, b1, W1, W2, hwsB, n);
    k_agg2<<<nblk128, BLK, 0, stream>>>(hwsB, offs, degi, srcs, dinv, b2, W3, hws3, pool, n);
    k_agg3<<<nblk128, BLK, 0, stream>>>(hws3, offs, degi, srcs, dinv, b3, choices, cbuf, bmax, bsum, n);

    // ---- softmax combine fused into final ----
    k_final<<<nblkN, BLK, 0, stream>>>(cbuf, choices, bmax, bsum, pool, fcw, fcb, out, nblk128, n);
}